// Round 1
// baseline (795.820 us; speedup 1.0000x reference)
//
#include <hip/hip_runtime.h>
#include <stdint.h>

#ifndef JAX_PARTITIONABLE
#define JAX_PARTITIONABLE 1   // JAX >= 0.5 default threefry_partitionable
#endif

// ---------------- problem sizes ----------------
static constexpr int BZ   = 8;
static constexpr int QD   = 512;
static constexpr int DIM  = 1024;
static constexpr int NFR  = 16;     // numc * numf_per_c frames
static constexpr int I2   = 64;     // bz * topk * numf_per_c pseudo-batch
static constexpr int TOPJ = 128;
static constexpr int NROW = I2 * 256;   // 16384 rows of reg-K

// ---------------- ws layout (float offsets) ----------------
static constexpr size_t OQS   = 0;          // Qp_seg   8*1024
static constexpr size_t OQR   = 8192;       // Qp_reg   8*1024
static constexpr size_t OGQ   = 16384;      // g⊙Qp_reg 8*1024
static constexpr size_t OSG   = 24576;      // Σ gQ     8
static constexpr size_t OCL   = 24584;      // Σ βQ     8
static constexpr size_t OMS   = 24592;      // seg masks 8*2*4
static constexpr size_t OP2   = 24656;      // probs2   64*256
static constexpr size_t OPART = 41088;      // partial stats 16*16384*3
static constexpr size_t OSEL  = 1048576;    // sel 64*256*1024
// total = 17,825,792 floats = 71,303,168 bytes

// ---------------- threefry2x32 (JAX-exact) ----------------
__device__ __forceinline__ uint32_t rotl32(uint32_t v, int d){ return (v << d) | (v >> (32 - d)); }

__device__ __forceinline__ void tf2x32(uint32_t k0, uint32_t k1, uint32_t x0, uint32_t x1,
                                       uint32_t& o0, uint32_t& o1){
  const uint32_t ks2 = k0 ^ k1 ^ 0x1BD11BDAu;
  x0 += k0; x1 += k1;
#define TFR(r) x0 += x1; x1 = rotl32(x1, r); x1 ^= x0;
  TFR(13) TFR(15) TFR(26) TFR(6)
  x0 += k1;  x1 += ks2 + 1u;
  TFR(17) TFR(29) TFR(16) TFR(24)
  x0 += ks2; x1 += k0 + 2u;
  TFR(13) TFR(15) TFR(26) TFR(6)
  x0 += k0;  x1 += k1 + 3u;
  TFR(17) TFR(29) TFR(16) TFR(24)
  x0 += k1;  x1 += ks2 + 4u;
  TFR(13) TFR(15) TFR(26) TFR(6)
  x0 += ks2; x1 += k0 + 5u;
#undef TFR
  o0 = x0; o1 = x1;
}

// k1,k2 = jax.random.split(jax.random.key(42))
__device__ __forceinline__ void jax_keys(uint32_t& k1a, uint32_t& k1b, uint32_t& k2a, uint32_t& k2b){
#if JAX_PARTITIONABLE
  uint32_t a,b,c,d;
  tf2x32(0u, 42u, 0u, 0u, a, b);
  tf2x32(0u, 42u, 0u, 1u, c, d);
  k1a = a; k1b = b; k2a = c; k2b = d;
#else
  uint32_t a,b,c,d;
  tf2x32(0u, 42u, 0u, 2u, a, b);   // lane0: counts (0,2) -> (y00, y01)
  tf2x32(0u, 42u, 1u, 3u, c, d);   // lane1: counts (1,3) -> (y10, y11)
  k1a = a; k1b = c; k2a = b; k2b = d;
#endif
}

// u = jax.random.uniform(key, ..., minval=1e-20, maxval=1.0) at flat index idx (size S even, half_n = S/2)
__device__ __forceinline__ float jax_uniform(uint32_t ka, uint32_t kb, uint32_t idx, uint32_t half_n){
  uint32_t o0, o1, bits;
#if JAX_PARTITIONABLE
  (void)half_n;
  tf2x32(ka, kb, 0u, idx, o0, o1);
  bits = o0 ^ o1;
#else
  if (idx < half_n){ tf2x32(ka, kb, idx, idx + half_n, o0, o1); bits = o0; }
  else             { tf2x32(ka, kb, idx - half_n, idx, o0, o1); bits = o1; }
#endif
  float f = __uint_as_float((bits >> 9) | 0x3f800000u) - 1.0f;  // [0,1)
  f = f + 1e-20f;              // floats*(maxval-minval)+minval, (1.0f-1e-20f)==1.0f
  return fmaxf(f, 1e-20f);
}

// ---------------- block reductions (deterministic tree) ----------------
__device__ __forceinline__ float blk_sum(float v, float* red){
  const int tid = threadIdx.x;
  red[tid] = v; __syncthreads();
  #pragma unroll
  for (int s = 128; s > 0; s >>= 1){
    if (tid < s) red[tid] += red[tid + s];
    __syncthreads();
  }
  float r = red[0]; __syncthreads();
  return r;
}
__device__ __forceinline__ float blk_max(float v, float* red){
  const int tid = threadIdx.x;
  red[tid] = v; __syncthreads();
  #pragma unroll
  for (int s = 128; s > 0; s >>= 1){
    if (tid < s) red[tid] = fmaxf(red[tid], red[tid + s]);
    __syncthreads();
  }
  float r = red[0]; __syncthreads();
  return r;
}

// ---------------- K1: q-norm, Qp_seg, Qp_reg, gq, Σ-scalars ----------------
__global__ __launch_bounds__(256) void k_prep(
    const float* __restrict__ qf,
    const float* __restrict__ sWq, const float* __restrict__ sbq,
    const float* __restrict__ slnqg, const float* __restrict__ slnqb,
    const float* __restrict__ rWq, const float* __restrict__ rbq,
    const float* __restrict__ rlnqg, const float* __restrict__ rlnqb,
    const float* __restrict__ rlnkg, const float* __restrict__ rlnkb,
    float* __restrict__ ws)
{
  const int b = blockIdx.x, tid = threadIdx.x;
  __shared__ float qn[QD];
  __shared__ float red[256];
  float q0 = qf[b * QD + tid];
  float q1 = qf[b * QD + 256 + tid];
  float ss = blk_sum(q0*q0 + q1*q1, red);
  float nrm = sqrtf(ss);
  qn[tid] = q0 / nrm;
  qn[tid + 256] = q1 / nrm;
  __syncthreads();

  for (int sel = 0; sel < 2; ++sel){
    const float* W  = sel ? rWq   : sWq;
    const float* bq = sel ? rbq   : sbq;
    const float* g  = sel ? rlnqg : slnqg;
    const float* be = sel ? rlnqb : slnqb;
    float y[4];
    #pragma unroll
    for (int r = 0; r < 4; ++r){
      const int d = tid + (r << 8);
      const float* wr = W + (size_t)d * QD;
      float a = 0.f;
      for (int e = 0; e < QD; e += 4){
        float4 w4 = *(const float4*)(wr + e);
        a += qn[e]*w4.x + qn[e+1]*w4.y + qn[e+2]*w4.z + qn[e+3]*w4.w;
      }
      y[r] = a + bq[d];
    }
    float S = blk_sum(y[0] + y[1] + y[2] + y[3], red);
    float mu = S * (1.f / 1024.f);
    float pv = 0.f;
    #pragma unroll
    for (int r = 0; r < 4; ++r){ float dv = y[r] - mu; pv += dv * dv; }
    float V = blk_sum(pv, red);
    float sig = sqrtf(V * (1.f / 1024.f) + 1e-12f);
    float o[4];
    #pragma unroll
    for (int r = 0; r < 4; ++r){
      const int d = tid + (r << 8);
      o[r] = (y[r] - mu) / sig * g[d] + be[d];
      ws[(sel ? OQR : OQS) + (size_t)b * DIM + d] = o[r];
    }
    if (sel == 1){
      float sg = 0.f, cl = 0.f;
      #pragma unroll
      for (int r = 0; r < 4; ++r){
        const int d = tid + (r << 8);
        float gv = rlnkg[d] * o[r];
        ws[OGQ + (size_t)b * DIM + d] = gv;
        sg += gv;
        cl += rlnkb[d] * o[r];
      }
      float SG = blk_sum(sg, red);
      float CL = blk_sum(cl, red);
      if (tid == 0){ ws[OSG + b] = SG; ws[OCL + b] = CL; }
    }
    __syncthreads();
  }
}

// ---------------- K2: seg_feat, Kp_seg, seg probs, gumbel masks ----------------
__global__ __launch_bounds__(256) void k_seg(
    const float* __restrict__ vcls,
    const float* __restrict__ sWk, const float* __restrict__ sbk,
    const float* __restrict__ slnkg, const float* __restrict__ slnkb,
    float* __restrict__ ws)
{
  const int b = blockIdx.x, tid = threadIdx.x;
  __shared__ float sf[4][DIM];
  __shared__ float yy[4][DIM];
  __shared__ float red[256];
  __shared__ float lg[4];

  #pragma unroll
  for (int r = 0; r < 4; ++r)
    #pragma unroll
    for (int c = 0; c < 4; ++c) sf[c][tid + (r << 8)] = 0.f;

  for (int f = 0; f < NFR; ++f){
    float v[4]; float s2 = 0.f;
    #pragma unroll
    for (int r = 0; r < 4; ++r){
      v[r] = vcls[((size_t)(b * NFR + f)) * DIM + tid + (r << 8)];
      s2 += v[r] * v[r];
    }
    float ss = blk_sum(s2, red);
    float nrm = sqrtf(ss);
    const int c = f >> 2;
    #pragma unroll
    for (int r = 0; r < 4; ++r) sf[c][tid + (r << 8)] += v[r] / nrm;
  }
  #pragma unroll
  for (int r = 0; r < 4; ++r)
    #pragma unroll
    for (int c = 0; c < 4; ++c) sf[c][tid + (r << 8)] *= 0.25f;
  __syncthreads();

  for (int r = 0; r < 4; ++r){
    const int d = tid + (r << 8);
    const float* wr = sWk + (size_t)d * DIM;
    float a0 = 0.f, a1 = 0.f, a2 = 0.f, a3 = 0.f;
    for (int e = 0; e < DIM; e += 4){
      float4 w4 = *(const float4*)(wr + e);
      a0 += sf[0][e]*w4.x + sf[0][e+1]*w4.y + sf[0][e+2]*w4.z + sf[0][e+3]*w4.w;
      a1 += sf[1][e]*w4.x + sf[1][e+1]*w4.y + sf[1][e+2]*w4.z + sf[1][e+3]*w4.w;
      a2 += sf[2][e]*w4.x + sf[2][e+1]*w4.y + sf[2][e+2]*w4.z + sf[2][e+3]*w4.w;
      a3 += sf[3][e]*w4.x + sf[3][e+1]*w4.y + sf[3][e+2]*w4.z + sf[3][e+3]*w4.w;
    }
    float bkd = sbk[d];
    yy[0][d] = a0 + bkd; yy[1][d] = a1 + bkd; yy[2][d] = a2 + bkd; yy[3][d] = a3 + bkd;
  }
  __syncthreads();

  for (int c = 0; c < 4; ++c){
    float t4 = 0.f;
    #pragma unroll
    for (int r = 0; r < 4; ++r) t4 += yy[c][tid + (r << 8)];
    float S = blk_sum(t4, red);
    float mu = S * (1.f / 1024.f);
    float pv = 0.f;
    #pragma unroll
    for (int r = 0; r < 4; ++r){ float dv = yy[c][tid + (r << 8)] - mu; pv += dv * dv; }
    float V = blk_sum(pv, red);
    float sig = sqrtf(V * (1.f / 1024.f) + 1e-12f);
    float lp = 0.f;
    #pragma unroll
    for (int r = 0; r < 4; ++r){
      const int d = tid + (r << 8);
      float kp = (yy[c][d] - mu) / sig * slnkg[d] + slnkb[d];
      lp += kp * ws[OQS + (size_t)b * DIM + d];
    }
    float L = blk_sum(lp, red);
    if (tid == 0) lg[c] = L;
  }
  __syncthreads();

  if (tid == 0){
    float m = fmaxf(fmaxf(lg[0], lg[1]), fmaxf(lg[2], lg[3]));
    float e[4], s = 0.f;
    #pragma unroll
    for (int c = 0; c < 4; ++c){ e[c] = expf(lg[c] - m); s += e[c]; }
    float probs[4];
    #pragma unroll
    for (int c = 0; c < 4; ++c) probs[c] = e[c] / s;
    uint32_t k1a, k1b, k2a, k2b;
    jax_keys(k1a, k1b, k2a, k2b);
    for (int t = 0; t < 2; ++t){
      float x[4];
      #pragma unroll
      for (int c = 0; c < 4; ++c){
        float u = jax_uniform(k1a, k1b, (uint32_t)(b * 8 + t * 4 + c), 32u);
        float gmb = -logf(-logf(u));
        x[c] = (probs[c] + gmb) / 1e-6f;
      }
      float xm = fmaxf(fmaxf(x[0], x[1]), fmaxf(x[2], x[3]));
      float w[4], sw = 0.f;
      #pragma unroll
      for (int c = 0; c < 4; ++c){ w[c] = expf(x[c] - xm); sw += w[c]; }
      #pragma unroll
      for (int c = 0; c < 4; ++c) ws[OMS + b * 8 + t * 4 + c] = w[c] / sw;
    }
  }
}

// ---------------- K3: sel = masks ⊛ image_embeds ----------------
__global__ __launch_bounds__(256) void k_sel(const float* __restrict__ E,
                                             float* __restrict__ ws)
{
  const int bid = blockIdx.x;
  const int i = bid >> 8, p = bid & 255;
  const int b = i >> 3, it = i & 7, t = it >> 2, j = it & 3;
  const int d = threadIdx.x << 2;
  const float* msk = ws + OMS + b * 8 + t * 4;
  float4 acc = {0.f, 0.f, 0.f, 0.f};
  #pragma unroll
  for (int c = 0; c < 4; ++c){
    const float w = msk[c];
    if (w != 0.f){
      const float4 v = *(const float4*)&E[(((size_t)((b * 4 + c) * 4 + j)) * 256 + p) * DIM + d];
      acc.x += w * v.x; acc.y += w * v.y; acc.z += w * v.z; acc.w += w * v.w;
    }
  }
  *(float4*)&ws[OSEL + ((size_t)(i * 256 + p)) * DIM + d] = acc;
}

// ---------------- K4: GEMM (sel @ reg_Wk^T + bk) with fused LN/logit stats ----------------
__global__ __launch_bounds__(256) void k_gemm(const float* __restrict__ W,
                                              const float* __restrict__ bk,
                                              float* __restrict__ ws)
{
  __shared__ __align__(16) float AsT[32][68];
  __shared__ __align__(16) float BsT[32][68];
  __shared__ float ps[3][64][16];
  const float* A  = ws + OSEL;
  const float* gq = ws + OGQ;
  float* part = ws + OPART;

  const int ct = blockIdx.x;          // 0..15
  const int rt = blockIdx.y;          // 0..255
  const int R0 = rt * 64, C0 = ct * 64;
  const int tid = threadIdx.x;
  const int ty = tid >> 4, tx = tid & 15;
  const int lr = tid >> 3;            // 0..31
  const int lk = (tid & 7) << 2;      // 0..28

  float acc[4][4] = {{0.f}};

  const float* Ar0 = A + (size_t)(R0 + lr) * DIM + lk;
  const float* Ar1 = A + (size_t)(R0 + lr + 32) * DIM + lk;
  const float* Br0 = W + (size_t)(C0 + lr) * DIM + lk;
  const float* Br1 = W + (size_t)(C0 + lr + 32) * DIM + lk;

  for (int kt = 0; kt < DIM; kt += 32){
    float4 a0 = *(const float4*)(Ar0 + kt);
    float4 a1 = *(const float4*)(Ar1 + kt);
    float4 b0 = *(const float4*)(Br0 + kt);
    float4 b1 = *(const float4*)(Br1 + kt);
    __syncthreads();
    AsT[lk+0][lr] = a0.x; AsT[lk+1][lr] = a0.y; AsT[lk+2][lr] = a0.z; AsT[lk+3][lr] = a0.w;
    AsT[lk+0][lr+32] = a1.x; AsT[lk+1][lr+32] = a1.y; AsT[lk+2][lr+32] = a1.z; AsT[lk+3][lr+32] = a1.w;
    BsT[lk+0][lr] = b0.x; BsT[lk+1][lr] = b0.y; BsT[lk+2][lr] = b0.z; BsT[lk+3][lr] = b0.w;
    BsT[lk+0][lr+32] = b1.x; BsT[lk+1][lr+32] = b1.y; BsT[lk+2][lr+32] = b1.z; BsT[lk+3][lr+32] = b1.w;
    __syncthreads();
    #pragma unroll
    for (int k = 0; k < 32; ++k){
      float av[4], bv[4];
      *(float4*)av = *(const float4*)&AsT[k][ty << 2];
      *(float4*)bv = *(const float4*)&BsT[k][tx << 2];
      #pragma unroll
      for (int i2 = 0; i2 < 4; ++i2)
        #pragma unroll
        for (int j = 0; j < 4; ++j)
          acc[i2][j] = fmaf(av[i2], bv[j], acc[i2][j]);
    }
  }

  const int b = R0 >> 11;   // 2048 rows per batch
  float bk4[4], g4[4];
  #pragma unroll
  for (int j = 0; j < 4; ++j){
    bk4[j] = bk[C0 + (tx << 2) + j];
    g4[j]  = gq[(size_t)b * DIM + C0 + (tx << 2) + j];
  }
  #pragma unroll
  for (int i2 = 0; i2 < 4; ++i2){
    float s = 0.f, q = 0.f, t = 0.f;
    #pragma unroll
    for (int j = 0; j < 4; ++j){
      float y = acc[i2][j] + bk4[j];
      s += y; q += y * y; t += y * g4[j];
    }
    ps[0][(ty << 2) + i2][tx] = s;
    ps[1][(ty << 2) + i2][tx] = q;
    ps[2][(ty << 2) + i2][tx] = t;
  }
  __syncthreads();
  if (tid < 64){
    #pragma unroll
    for (int st = 0; st < 3; ++st){
      float v = 0.f;
      #pragma unroll
      for (int x = 0; x < 16; ++x) v += ps[st][tid][x];
      part[((size_t)ct * NROW + R0 + tid) * 3 + st] = v;
    }
  }
}

// ---------------- K5: finalize logits, softmax over 256 positions ----------------
__global__ __launch_bounds__(256) void k_probs2(float* __restrict__ ws)
{
  const int i = blockIdx.x, tid = threadIdx.x;
  const int r = i * 256 + tid;
  const int b = i >> 3;
  __shared__ float red[256];
  const float* part = ws + OPART;
  float S = 0.f, Q = 0.f, T = 0.f;
  for (int ct = 0; ct < 16; ++ct){
    const float* pp = part + ((size_t)ct * NROW + r) * 3;
    S += pp[0]; Q += pp[1]; T += pp[2];
  }
  float mu  = S * (1.f / 1024.f);
  float var = Q * (1.f / 1024.f) - mu * mu;
  float sig = sqrtf(var + 1e-12f);
  float L = (T - mu * ws[OSG + b]) / sig + ws[OCL + b];
  float M = blk_max(L, red);
  float w = expf(L - M);
  float sw = blk_sum(w, red);
  ws[OP2 + r] = w / sw;
}

// ---------------- K6: reg gumbel + weighted gather -> out ----------------
__global__ __launch_bounds__(256) void k_out(const float* __restrict__ ws,
                                             float* __restrict__ out)
{
  const int bid = blockIdx.x;
  const int i = bid >> 7, t2 = bid & 127;
  const int tid = threadIdx.x;
  __shared__ float red[256];
  __shared__ float wv[256];
  __shared__ unsigned long long mk[4];

  uint32_t k1a, k1b, k2a, k2b;
  jax_keys(k1a, k1b, k2a, k2b);
  const uint32_t fidx = ((uint32_t)(i * TOPJ + t2)) * 256u + (uint32_t)tid;
  float u = jax_uniform(k2a, k2b, fidx, 1048576u);   // S = 64*128*256, half = S/2
  float gmb = -logf(-logf(u));
  float x = (ws[OP2 + (size_t)i * 256 + tid] + gmb) / 1e-6f;
  float M = blk_max(x, red);
  float w = expf(x - M);
  float sw = blk_sum(w, red);
  float wn = w / sw;
  wv[tid] = wn;
  unsigned long long bal = __ballot(wn != 0.f);
  if ((tid & 63) == 0) mk[tid >> 6] = bal;
  __syncthreads();

  const int d = tid << 2;
  float4 acc = {0.f, 0.f, 0.f, 0.f};
  const float* selb = ws + OSEL + (size_t)i * 256 * DIM;
  for (int wq = 0; wq < 4; ++wq){
    unsigned long long mm = mk[wq];
    while (mm){
      const int l = __ffsll(mm) - 1;
      mm &= mm - 1;
      const int p = (wq << 6) + l;
      const float wp = wv[p];
      const float4 v = *(const float4*)&selb[(size_t)p * DIM + d];
      acc.x += wp * v.x; acc.y += wp * v.y; acc.z += wp * v.z; acc.w += wp * v.w;
    }
  }
  *(float4*)&out[((size_t)(i * TOPJ + t2)) * DIM + d] = acc;
}

// ---------------- launch ----------------
extern "C" void kernel_launch(void* const* d_in, const int* in_sizes, int n_in,
                              void* d_out, int out_size, void* d_ws, size_t ws_size,
                              hipStream_t stream)
{
  const float* qf    = (const float*)d_in[0];
  const float* E     = (const float*)d_in[1];
  const float* vcls  = (const float*)d_in[2];
  const float* sWq   = (const float*)d_in[3];
  const float* sbq   = (const float*)d_in[4];
  const float* slnqg = (const float*)d_in[5];
  const float* slnqb = (const float*)d_in[6];
  const float* sWk   = (const float*)d_in[7];
  const float* sbk   = (const float*)d_in[8];
  const float* slnkg = (const float*)d_in[9];
  const float* slnkb = (const float*)d_in[10];
  const float* rWq   = (const float*)d_in[11];
  const float* rbq   = (const float*)d_in[12];
  const float* rlnqg = (const float*)d_in[13];
  const float* rlnqb = (const float*)d_in[14];
  const float* rWk   = (const float*)d_in[15];
  const float* rbk   = (const float*)d_in[16];
  const float* rlnkg = (const float*)d_in[17];
  const float* rlnkb = (const float*)d_in[18];
  float* ws  = (float*)d_ws;
  float* out = (float*)d_out;

  k_prep<<<BZ, 256, 0, stream>>>(qf, sWq, sbq, slnqg, slnqb,
                                 rWq, rbq, rlnqg, rlnqb, rlnkg, rlnkb, ws);
  k_seg<<<BZ, 256, 0, stream>>>(vcls, sWk, sbk, slnkg, slnkb, ws);
  k_sel<<<I2 * 256, 256, 0, stream>>>(E, ws);
  k_gemm<<<dim3(16, 256), 256, 0, stream>>>(rWk, rbk, ws);
  k_probs2<<<I2, 256, 0, stream>>>(ws);
  k_out<<<I2 * TOPJ, 256, 0, stream>>>(ws, out);
}

// Round 2
// 361.464 us; speedup vs baseline: 2.2017x; 2.2017x over previous
//
#include <hip/hip_runtime.h>
#include <hip/hip_fp16.h>
#include <stdint.h>

#ifndef JAX_PARTITIONABLE
#define JAX_PARTITIONABLE 1   // JAX >= 0.5 default threefry_partitionable
#endif

typedef _Float16 f16x8 __attribute__((ext_vector_type(8)));
typedef float    f32x4 __attribute__((ext_vector_type(4)));

// ---------------- problem sizes ----------------
static constexpr int BZ   = 8;
static constexpr int QD   = 512;
static constexpr int DIM  = 1024;
static constexpr int I2   = 64;
static constexpr int TOPJ = 128;
static constexpr int NROW = 16384;

// ---------------- ws layout ----------------
// ushort region: AH[16384*1024], AL[16384*1024], WH[1024*1024], WL[1024*1024]
static constexpr size_t EAH = 0;
static constexpr size_t EAL = (size_t)16384 * 1024;            // 16,777,216
static constexpr size_t EWH = EAL * 2;                         // 33,554,432
static constexpr size_t EWL = EWH + (size_t)1024 * 1024;       // 34,603,008
// float region starts at byte 71,303,168 = float index 17,825,792
static constexpr size_t FQN   = 17825792;            // 8*512
static constexpr size_t FSF   = FQN + 4096;          // 8*4*1024
static constexpr size_t FYS   = FSF + 32768;         // 8*1024
static constexpr size_t FYR   = FYS + 8192;          // 8*1024
static constexpr size_t FY2   = FYR + 8192;          // 8*4*1024
static constexpr size_t FGQ   = FY2 + 32768;         // 8*1024
static constexpr size_t FSG   = FGQ + 8192;          // 8
static constexpr size_t FCL   = FSG + 8;             // 8
static constexpr size_t FMS   = FCL + 8;             // 8*2*4
static constexpr size_t FP2   = FMS + 64;            // 64*256
static constexpr size_t FPART = FP2 + 16384;         // 2*16384*3
// end = 18,034,768 floats = 72.1 MB

// ---------------- threefry2x32 (JAX-exact) ----------------
__device__ __forceinline__ uint32_t rotl32(uint32_t v, int d){ return (v << d) | (v >> (32 - d)); }

__device__ __forceinline__ void tf2x32(uint32_t k0, uint32_t k1, uint32_t x0, uint32_t x1,
                                       uint32_t& o0, uint32_t& o1){
  const uint32_t ks2 = k0 ^ k1 ^ 0x1BD11BDAu;
  x0 += k0; x1 += k1;
#define TFR(r) x0 += x1; x1 = rotl32(x1, r); x1 ^= x0;
  TFR(13) TFR(15) TFR(26) TFR(6)
  x0 += k1;  x1 += ks2 + 1u;
  TFR(17) TFR(29) TFR(16) TFR(24)
  x0 += ks2; x1 += k0 + 2u;
  TFR(13) TFR(15) TFR(26) TFR(6)
  x0 += k0;  x1 += k1 + 3u;
  TFR(17) TFR(29) TFR(16) TFR(24)
  x0 += k1;  x1 += ks2 + 4u;
  TFR(13) TFR(15) TFR(26) TFR(6)
  x0 += ks2; x1 += k0 + 5u;
#undef TFR
  o0 = x0; o1 = x1;
}

__device__ __forceinline__ void jax_keys(uint32_t& k1a, uint32_t& k1b, uint32_t& k2a, uint32_t& k2b){
#if JAX_PARTITIONABLE
  uint32_t a,b,c,d;
  tf2x32(0u, 42u, 0u, 0u, a, b);
  tf2x32(0u, 42u, 0u, 1u, c, d);
  k1a = a; k1b = b; k2a = c; k2b = d;
#else
  uint32_t a,b,c,d;
  tf2x32(0u, 42u, 0u, 2u, a, b);
  tf2x32(0u, 42u, 1u, 3u, c, d);
  k1a = a; k1b = c; k2a = b; k2b = d;
#endif
}

__device__ __forceinline__ float jax_uniform(uint32_t ka, uint32_t kb, uint32_t idx, uint32_t half_n){
  uint32_t o0, o1, bits;
#if JAX_PARTITIONABLE
  (void)half_n;
  tf2x32(ka, kb, 0u, idx, o0, o1);
  bits = o0 ^ o1;
#else
  if (idx < half_n){ tf2x32(ka, kb, idx, idx + half_n, o0, o1); bits = o0; }
  else             { tf2x32(ka, kb, idx - half_n, idx, o0, o1); bits = o1; }
#endif
  float f = __uint_as_float((bits >> 9) | 0x3f800000u) - 1.0f;
  f = f + 1e-20f;
  return fmaxf(f, 1e-20f);
}

// ---------------- block reductions ----------------
__device__ __forceinline__ float blk_sum(float v, float* red){
  const int tid = threadIdx.x;
  red[tid] = v; __syncthreads();
  #pragma unroll
  for (int s = 128; s > 0; s >>= 1){
    if (tid < s) red[tid] += red[tid + s];
    __syncthreads();
  }
  float r = red[0]; __syncthreads();
  return r;
}
__device__ __forceinline__ float blk_max(float v, float* red){
  const int tid = threadIdx.x;
  red[tid] = v; __syncthreads();
  #pragma unroll
  for (int s = 128; s > 0; s >>= 1){
    if (tid < s) red[tid] = fmaxf(red[tid], red[tid + s]);
    __syncthreads();
  }
  float r = red[0]; __syncthreads();
  return r;
}

// ---------------- fp16 split helpers ----------------
__device__ __forceinline__ unsigned short f2h(float x){
  return __half_as_ushort(__float2half(x));
}
__device__ __forceinline__ float h2f(unsigned short u){
  return __half2float(__ushort_as_half(u));
}

// ---------------- async global->LDS (16B/lane) ----------------
__device__ __forceinline__ void gl_lds16(const void* g, void* l){
  __builtin_amdgcn_global_load_lds((const __attribute__((address_space(1))) void*)g,
                                   (__attribute__((address_space(3))) void*)l, 16, 0, 0);
}

// ================= K1: norms (q, video_cls) -> qn, seg_feat =================
__global__ __launch_bounds__(256) void k_norm(const float* __restrict__ qf,
                                              const float* __restrict__ vcls,
                                              float* __restrict__ ws)
{
  const int b = blockIdx.x, tid = threadIdx.x;
  __shared__ float red[256];
  float q0 = qf[b * QD + tid];
  float q1 = qf[b * QD + 256 + tid];
  float ss = blk_sum(q0*q0 + q1*q1, red);
  float nrm = sqrtf(ss);
  ws[FQN + (size_t)b * QD + tid]       = q0 / nrm;
  ws[FQN + (size_t)b * QD + 256 + tid] = q1 / nrm;

  float sf[4][4];
  #pragma unroll
  for (int c = 0; c < 4; ++c)
    #pragma unroll
    for (int r = 0; r < 4; ++r) sf[c][r] = 0.f;

  for (int f = 0; f < 16; ++f){
    float v[4]; float s2 = 0.f;
    #pragma unroll
    for (int r = 0; r < 4; ++r){
      v[r] = vcls[((size_t)(b * 16 + f)) * DIM + tid + (r << 8)];
      s2 += v[r] * v[r];
    }
    float s = blk_sum(s2, red);
    float n2 = sqrtf(s);
    const int c = f >> 2;
    #pragma unroll
    for (int r = 0; r < 4; ++r) sf[c][r] += v[r] / n2;
  }
  #pragma unroll
  for (int c = 0; c < 4; ++c)
    #pragma unroll
    for (int r = 0; r < 4; ++r)
      ws[FSF + ((size_t)(b * 4 + c)) * DIM + tid + (r << 8)] = sf[c][r] * 0.25f;
}

// ================= K2: W split to fp16 hi/lo =================
__global__ __launch_bounds__(256) void k_wsplit(const float* __restrict__ W,
                                                float* __restrict__ ws)
{
  unsigned short* WH = (unsigned short*)ws + EWH;
  unsigned short* WL = (unsigned short*)ws + EWL;
  const size_t idx = ((size_t)blockIdx.x * 256 + threadIdx.x) * 4;
  float4 v = *(const float4*)&W[idx];
  ushort4 h, l;
  h.x = f2h(v.x); l.x = f2h(v.x - h2f(h.x));
  h.y = f2h(v.y); l.y = f2h(v.y - h2f(h.y));
  h.z = f2h(v.z); l.z = f2h(v.z - h2f(h.z));
  h.w = f2h(v.w); l.w = f2h(v.w - h2f(h.w));
  *(ushort4*)&WH[idx] = h;
  *(ushort4*)&WL[idx] = l;
}

// ================= K3: distributed matvecs =================
__global__ __launch_bounds__(256) void k_matvec(
    const float* __restrict__ sWq, const float* __restrict__ sbq,
    const float* __restrict__ rWq, const float* __restrict__ rbq,
    const float* __restrict__ sWk, const float* __restrict__ sbk,
    float* __restrict__ ws)
{
  const int bid = blockIdx.x;
  const int b = bid >> 5, ch = bid & 31;
  const int tid = threadIdx.x;
  const int di = tid >> 3, sub = tid & 7;
  const int d = ch * 32 + di;
  const float* qn = ws + FQN + (size_t)b * QD;
  const float* sf = ws + FSF + (size_t)b * 4 * DIM;

  // y_seg = qn . sWq[d,:]
  {
    const float* wr = sWq + (size_t)d * QD + sub * 64;
    const float* qq = qn + sub * 64;
    float a = 0.f;
    #pragma unroll
    for (int e = 0; e < 64; e += 4){
      float4 w4 = *(const float4*)(wr + e);
      a += qq[e]*w4.x + qq[e+1]*w4.y + qq[e+2]*w4.z + qq[e+3]*w4.w;
    }
    a += __shfl_xor(a, 1); a += __shfl_xor(a, 2); a += __shfl_xor(a, 4);
    if (sub == 0) ws[FYS + (size_t)b * DIM + d] = a + sbq[d];
  }
  // y_reg = qn . rWq[d,:]
  {
    const float* wr = rWq + (size_t)d * QD + sub * 64;
    const float* qq = qn + sub * 64;
    float a = 0.f;
    #pragma unroll
    for (int e = 0; e < 64; e += 4){
      float4 w4 = *(const float4*)(wr + e);
      a += qq[e]*w4.x + qq[e+1]*w4.y + qq[e+2]*w4.z + qq[e+3]*w4.w;
    }
    a += __shfl_xor(a, 1); a += __shfl_xor(a, 2); a += __shfl_xor(a, 4);
    if (sub == 0) ws[FYR + (size_t)b * DIM + d] = a + rbq[d];
  }
  // y2[c] = sf[c] . sWk[d,:]
  for (int c = 0; c < 4; ++c){
    const float* wr = sWk + (size_t)d * DIM + sub * 128;
    const float* qq = sf + (size_t)c * DIM + sub * 128;
    float a = 0.f;
    #pragma unroll
    for (int e = 0; e < 128; e += 4){
      float4 w4 = *(const float4*)(wr + e);
      a += qq[e]*w4.x + qq[e+1]*w4.y + qq[e+2]*w4.z + qq[e+3]*w4.w;
    }
    a += __shfl_xor(a, 1); a += __shfl_xor(a, 2); a += __shfl_xor(a, 4);
    if (sub == 0) ws[FY2 + ((size_t)(b * 4 + c)) * DIM + d] = a + sbk[d];
  }
}

// ================= K4: LN finishers + seg softmax/gumbel masks =================
__global__ __launch_bounds__(256) void k_post(
    const float* __restrict__ slnqg, const float* __restrict__ slnqb,
    const float* __restrict__ rlnqg, const float* __restrict__ rlnqb,
    const float* __restrict__ rlnkg, const float* __restrict__ rlnkb,
    const float* __restrict__ slnkg, const float* __restrict__ slnkb,
    float* __restrict__ ws)
{
  const int b = blockIdx.x, tid = threadIdx.x;
  __shared__ float red[256];
  __shared__ float qps[DIM];
  __shared__ float lg[4];

  // LN(y_seg) -> qps (Qp_seg, local only)
  {
    float y[4];
    #pragma unroll
    for (int r = 0; r < 4; ++r) y[r] = ws[FYS + (size_t)b * DIM + tid + (r << 8)];
    float S = blk_sum(y[0]+y[1]+y[2]+y[3], red);
    float mu = S * (1.f / 1024.f);
    float pv = 0.f;
    #pragma unroll
    for (int r = 0; r < 4; ++r){ float dv = y[r]-mu; pv += dv*dv; }
    float V = blk_sum(pv, red);
    float sig = sqrtf(V * (1.f / 1024.f) + 1e-12f);
    #pragma unroll
    for (int r = 0; r < 4; ++r){
      const int d = tid + (r << 8);
      qps[d] = (y[r]-mu)/sig * slnqg[d] + slnqb[d];
    }
  }
  __syncthreads();

  // LN(y_reg) -> gq, SG, CL
  {
    float y[4];
    #pragma unroll
    for (int r = 0; r < 4; ++r) y[r] = ws[FYR + (size_t)b * DIM + tid + (r << 8)];
    float S = blk_sum(y[0]+y[1]+y[2]+y[3], red);
    float mu = S * (1.f / 1024.f);
    float pv = 0.f;
    #pragma unroll
    for (int r = 0; r < 4; ++r){ float dv = y[r]-mu; pv += dv*dv; }
    float V = blk_sum(pv, red);
    float sig = sqrtf(V * (1.f / 1024.f) + 1e-12f);
    float sg = 0.f, cl = 0.f;
    #pragma unroll
    for (int r = 0; r < 4; ++r){
      const int d = tid + (r << 8);
      float o = (y[r]-mu)/sig * rlnqg[d] + rlnqb[d];
      float gv = rlnkg[d] * o;
      ws[FGQ + (size_t)b * DIM + d] = gv;
      sg += gv;
      cl += rlnkb[d] * o;
    }
    float SG = blk_sum(sg, red);
    float CL = blk_sum(cl, red);
    if (tid == 0){ ws[FSG + b] = SG; ws[FCL + b] = CL; }
  }

  // per segment c: LN(y2) -> Kp, logit
  for (int c = 0; c < 4; ++c){
    float y[4];
    #pragma unroll
    for (int r = 0; r < 4; ++r) y[r] = ws[FY2 + ((size_t)(b * 4 + c)) * DIM + tid + (r << 8)];
    float S = blk_sum(y[0]+y[1]+y[2]+y[3], red);
    float mu = S * (1.f / 1024.f);
    float pv = 0.f;
    #pragma unroll
    for (int r = 0; r < 4; ++r){ float dv = y[r]-mu; pv += dv*dv; }
    float V = blk_sum(pv, red);
    float sig = sqrtf(V * (1.f / 1024.f) + 1e-12f);
    float lp = 0.f;
    #pragma unroll
    for (int r = 0; r < 4; ++r){
      const int d = tid + (r << 8);
      float kp = (y[r]-mu)/sig * slnkg[d] + slnkb[d];
      lp += kp * qps[d];
    }
    float L = blk_sum(lp, red);
    if (tid == 0) lg[c] = L;
  }
  __syncthreads();

  if (tid == 0){
    float m = fmaxf(fmaxf(lg[0], lg[1]), fmaxf(lg[2], lg[3]));
    float e[4], s = 0.f;
    #pragma unroll
    for (int c = 0; c < 4; ++c){ e[c] = expf(lg[c] - m); s += e[c]; }
    float probs[4];
    #pragma unroll
    for (int c = 0; c < 4; ++c) probs[c] = e[c] / s;
    uint32_t k1a, k1b, k2a, k2b;
    jax_keys(k1a, k1b, k2a, k2b);
    for (int t = 0; t < 2; ++t){
      float x[4];
      #pragma unroll
      for (int c = 0; c < 4; ++c){
        float u = jax_uniform(k1a, k1b, (uint32_t)(b * 8 + t * 4 + c), 32u);
        float gmb = -logf(-logf(u));
        x[c] = (probs[c] + gmb) / 1e-6f;
      }
      float xm = fmaxf(fmaxf(x[0], x[1]), fmaxf(x[2], x[3]));
      float w[4], sw = 0.f;
      #pragma unroll
      for (int c = 0; c < 4; ++c){ w[c] = expf(x[c] - xm); sw += w[c]; }
      #pragma unroll
      for (int c = 0; c < 4; ++c) ws[FMS + b * 8 + t * 4 + c] = w[c] / sw;
    }
  }
}

// ================= K5: sel rows -> fp16 hi/lo (A matrix) =================
__global__ __launch_bounds__(256) void k_sel(const float* __restrict__ E,
                                             float* __restrict__ ws)
{
  const int bid = blockIdx.x;
  const int i = bid >> 8, p = bid & 255;
  const int bz = i >> 3, it = i & 7, t = it >> 2, j = it & 3;
  const int d = threadIdx.x << 2;
  const float* msk = ws + FMS + bz * 8 + t * 4;
  float4 a = {0.f, 0.f, 0.f, 0.f};
  #pragma unroll
  for (int c = 0; c < 4; ++c){
    const float w = msk[c];
    if (w != 0.f){
      const float4 v = *(const float4*)&E[(((size_t)((bz * 4 + c) * 4 + j)) * 256 + p) * DIM + d];
      a.x += w * v.x; a.y += w * v.y; a.z += w * v.z; a.w += w * v.w;
    }
  }
  unsigned short* AH = (unsigned short*)ws + EAH;
  unsigned short* AL = (unsigned short*)ws + EAL;
  const size_t o = ((size_t)(i * 256 + p)) * DIM + d;
  ushort4 h, l;
  h.x = f2h(a.x); l.x = f2h(a.x - h2f(h.x));
  h.y = f2h(a.y); l.y = f2h(a.y - h2f(h.y));
  h.z = f2h(a.z); l.z = f2h(a.z - h2f(h.z));
  h.w = f2h(a.w); l.w = f2h(a.w - h2f(h.w));
  *(ushort4*)&AH[o] = h;
  *(ushort4*)&AL[o] = l;
}

// ================= K6: split-fp16 MFMA GEMM with fused LN/logit stats =================
// tile 128x256, BK=32, hi/lo interleaved in 128B LDS rows, (row&7) XOR swizzle,
// double-buffered 2-phase, 8 waves (2x4).
__global__ __launch_bounds__(512, 2) void k_gemm(const float* __restrict__ bk,
                                                 float* __restrict__ ws)
{
  const unsigned short* AH = (const unsigned short*)ws + EAH;
  const unsigned short* AL = (const unsigned short*)ws + EAL;
  const unsigned short* WH = (const unsigned short*)ws + EWH;
  const unsigned short* WL = (const unsigned short*)ws + EWL;
  const float* gq = ws + FGQ;
  float* part = ws + FPART;

  __shared__ __align__(16) char lds[104448];   // 2 x (16KB A + 32KB B) + 6KB fred
  float* fred = (float*)(lds + 98304);

  const int rt = blockIdx.x;           // 0..127
  const int nh = blockIdx.y;           // 0..1
  const int R0 = rt * 128;
  const int tid = threadIdx.x;
  const int lane = tid & 63, wid = tid >> 6;
  const int wr = wid >> 2, wc = wid & 3;
  const int b = R0 >> 11;

  if (tid < 128){
    #pragma unroll
    for (int x = 0; x < 12; ++x) fred[tid * 12 + x] = 0.f;
  }

  // staging lane constants
  const int lr8  = lane >> 3;                    // 0..7
  const int cl   = (lane & 7) ^ lr8;             // logical 16B chunk 0..7
  const int koff = (cl & 3) * 8;                 // element offset within 32-elem half
  const bool chi = (cl < 4);

  // frag read lane constants
  const int rowa = wr * 64 + (lane & 15);
  const int rowb = wc * 64 + (lane & 15);
  const int pcH  = (((lane >> 4) + 0) ^ (lane & 7)) * 16;
  const int pcL  = (((lane >> 4) + 4) ^ (lane & 7)) * 16;

  f32x4 acc[4][4];

  for (int ct = 0; ct < 2; ++ct){
    const int C0 = (nh * 2 + ct) * 256;
    #pragma unroll
    for (int fm = 0; fm < 4; ++fm)
      #pragma unroll
      for (int fn = 0; fn < 4; ++fn)
        acc[fm][fn] = (f32x4){0.f, 0.f, 0.f, 0.f};

    auto stage = [&](int buf, int kt){
      const int base = buf * 49152;
      #pragma unroll
      for (int q = 0; q < 6; ++q){
        const int g = wid * 6 + q;
        if (g < 16){
          const int e = g;
          const int row = R0 + e * 8 + lr8;
          const unsigned short* src = (chi ? AH : AL) + (size_t)row * DIM + kt + koff;
          gl_lds16(src, lds + base + e * 1024);
        } else {
          const int e = g - 16;
          const int row = C0 + e * 8 + lr8;
          const unsigned short* src = (chi ? WH : WL) + (size_t)row * DIM + kt + koff;
          gl_lds16(src, lds + base + 16384 + e * 1024);
        }
      }
    };

    auto compute = [&](int buf){
      const int base = buf * 49152;
      const char* pa = lds + base;
      const char* pb = lds + base + 16384;
      f16x8 ah[4], al[4], bh[4], bl[4];
      #pragma unroll
      for (int fm = 0; fm < 4; ++fm){
        const int ro = (rowa + fm * 16) * 128;
        ah[fm] = *(const f16x8*)(pa + ro + pcH);
        al[fm] = *(const f16x8*)(pa + ro + pcL);
      }
      #pragma unroll
      for (int fn = 0; fn < 4; ++fn){
        const int ro = (rowb + fn * 16) * 128;
        bh[fn] = *(const f16x8*)(pb + ro + pcH);
        bl[fn] = *(const f16x8*)(pb + ro + pcL);
      }
      #pragma unroll
      for (int fm = 0; fm < 4; ++fm)
        #pragma unroll
        for (int fn = 0; fn < 4; ++fn){
          acc[fm][fn] = __builtin_amdgcn_mfma_f32_16x16x32_f16(ah[fm], bh[fn], acc[fm][fn], 0, 0, 0);
          acc[fm][fn] = __builtin_amdgcn_mfma_f32_16x16x32_f16(ah[fm], bl[fn], acc[fm][fn], 0, 0, 0);
          acc[fm][fn] = __builtin_amdgcn_mfma_f32_16x16x32_f16(al[fm], bh[fn], acc[fm][fn], 0, 0, 0);
        }
    };

    int cur = 0;
    stage(0, 0);
    __syncthreads();
    for (int t = 0; t < 32; ++t){
      if (t < 31) stage(cur ^ 1, (t + 1) * 32);
      compute(cur);
      __syncthreads();
      cur ^= 1;
    }

    // epilogue: per-row partial stats over this ct's 64 cols (per wave)
    float bkv[4], gv[4];
    #pragma unroll
    for (int fn = 0; fn < 4; ++fn){
      const int col = C0 + wc * 64 + fn * 16 + (lane & 15);
      bkv[fn] = bk[col];
      gv[fn]  = gq[(size_t)b * DIM + col];
    }
    #pragma unroll
    for (int fm = 0; fm < 4; ++fm)
      #pragma unroll
      for (int r = 0; r < 4; ++r){
        float s = 0.f, q = 0.f, tt = 0.f;
        #pragma unroll
        for (int fn = 0; fn < 4; ++fn){
          float y = acc[fm][fn][r] + bkv[fn];
          s += y; q += y * y; tt += y * gv[fn];
        }
        #pragma unroll
        for (int m = 8; m >= 1; m >>= 1){
          s += __shfl_xor(s, m); q += __shfl_xor(q, m); tt += __shfl_xor(tt, m);
        }
        if ((lane & 15) == 0){
          const int rl = wr * 64 + fm * 16 + (lane >> 4) * 4 + r;
          fred[(rl * 4 + wc) * 3 + 0] += s;
          fred[(rl * 4 + wc) * 3 + 1] += q;
          fred[(rl * 4 + wc) * 3 + 2] += tt;
        }
      }
    __syncthreads();
  }

  if (tid < 128){
    const int row = R0 + tid;
    #pragma unroll
    for (int st = 0; st < 3; ++st){
      float v = fred[(tid * 4 + 0) * 3 + st] + fred[(tid * 4 + 1) * 3 + st]
              + fred[(tid * 4 + 2) * 3 + st] + fred[(tid * 4 + 3) * 3 + st];
      part[((size_t)nh * NROW + row) * 3 + st] = v;
    }
  }
}

// ================= K7: finalize logits, softmax over 256 =================
__global__ __launch_bounds__(256) void k_probs2(float* __restrict__ ws)
{
  const int i = blockIdx.x, tid = threadIdx.x;
  const int r = i * 256 + tid;
  const int b = i >> 3;
  __shared__ float red[256];
  const float* part = ws + FPART;
  float S = part[(size_t)r * 3 + 0] + part[((size_t)NROW + r) * 3 + 0];
  float Q = part[(size_t)r * 3 + 1] + part[((size_t)NROW + r) * 3 + 1];
  float T = part[(size_t)r * 3 + 2] + part[((size_t)NROW + r) * 3 + 2];
  float mu  = S * (1.f / 1024.f);
  float var = Q * (1.f / 1024.f) - mu * mu;
  float sig = sqrtf(var + 1e-12f);
  float L = (T - mu * ws[FSG + b]) / sig + ws[FCL + b];
  float M = blk_max(L, red);
  float w = expf(L - M);
  float sw = blk_sum(w, red);
  ws[FP2 + r] = w / sw;
}

// ================= K8: reg gumbel + weighted gather -> out =================
__global__ __launch_bounds__(256) void k_out(const float* __restrict__ E,
                                             const float* __restrict__ ws,
                                             float* __restrict__ out)
{
  const int bid = blockIdx.x;
  const int i = bid >> 7, t2 = bid & 127;
  const int bz = i >> 3, it = i & 7, tt = it >> 2, j = it & 3;
  const int tid = threadIdx.x;
  __shared__ float red[256];
  __shared__ float wv[256];
  __shared__ float mloc[4];
  __shared__ unsigned long long mk[4];

  if (tid < 4) mloc[tid] = ws[FMS + bz * 8 + tt * 4 + tid];

  uint32_t k1a, k1b, k2a, k2b;
  jax_keys(k1a, k1b, k2a, k2b);
  const uint32_t fidx = ((uint32_t)(i * TOPJ + t2)) * 256u + (uint32_t)tid;
  float u = jax_uniform(k2a, k2b, fidx, 1048576u);
  float gmb = -logf(-logf(u));
  float x = (ws[FP2 + (size_t)i * 256 + tid] + gmb) / 1e-6f;
  float M = blk_max(x, red);
  float w = expf(x - M);
  float sw = blk_sum(w, red);
  float wn = w / sw;
  wv[tid] = wn;
  unsigned long long bal = __ballot(wn != 0.f);
  if ((tid & 63) == 0) mk[tid >> 6] = bal;
  __syncthreads();

  const int d = tid << 2;
  float4 acc = {0.f, 0.f, 0.f, 0.f};
  for (int wq = 0; wq < 4; ++wq){
    unsigned long long mm = mk[wq];
    while (mm){
      const int l = __ffsll(mm) - 1;
      mm &= mm - 1;
      const int p = (wq << 6) + l;
      const float wp = wv[p];
      #pragma unroll
      for (int c = 0; c < 4; ++c){
        const float mc = mloc[c];
        if (mc != 0.f){
          const float4 v = *(const float4*)&E[(((size_t)((bz * 4 + c) * 4 + j)) * 256 + p) * DIM + d];
          const float wm = wp * mc;
          acc.x += wm * v.x; acc.y += wm * v.y; acc.z += wm * v.z; acc.w += wm * v.w;
        }
      }
    }
  }
  *(float4*)&out[((size_t)(i * TOPJ + t2)) * DIM + d] = acc;
}

// ---------------- launch ----------------
extern "C" void kernel_launch(void* const* d_in, const int* in_sizes, int n_in,
                              void* d_out, int out_size, void* d_ws, size_t ws_size,
                              hipStream_t stream)
{
  const float* qf    = (const float*)d_in[0];
  const float* E     = (const float*)d_in[1];
  const float* vcls  = (const float*)d_in[2];
  const float* sWq   = (const float*)d_in[3];
  const float* sbq   = (const float*)d_in[4];
  const float* slnqg = (const float*)d_in[5];
  const float* slnqb = (const float*)d_in[6];
  const float* sWk   = (const float*)d_in[7];
  const float* sbk   = (const float*)d_in[8];
  const float* slnkg = (const float*)d_in[9];
  const float* slnkb = (const float*)d_in[10];
  const float* rWq   = (const float*)d_in[11];
  const float* rbq   = (const float*)d_in[12];
  const float* rlnqg = (const float*)d_in[13];
  const float* rlnqb = (const float*)d_in[14];
  const float* rWk   = (const float*)d_in[15];
  const float* rbk   = (const float*)d_in[16];
  const float* rlnkg = (const float*)d_in[17];
  const float* rlnkb = (const float*)d_in[18];
  float* ws  = (float*)d_ws;
  float* out = (float*)d_out;

  k_norm<<<BZ, 256, 0, stream>>>(qf, vcls, ws);
  k_wsplit<<<1024, 256, 0, stream>>>(rWk, ws);
  k_matvec<<<256, 256, 0, stream>>>(sWq, sbq, rWq, rbq, sWk, sbk, ws);
  k_post<<<BZ, 256, 0, stream>>>(slnqg, slnqb, rlnqg, rlnqb, rlnkg, rlnkb, slnkg, slnkb, ws);
  k_sel<<<I2 * 256, 256, 0, stream>>>(E, ws);
  k_gemm<<<dim3(128, 2), 512, 0, stream>>>(rbk, ws);
  k_probs2<<<I2, 256, 0, stream>>>(ws);
  k_out<<<I2 * TOPJ, 256, 0, stream>>>(E, ws, out);
}

// Round 3
// 243.421 us; speedup vs baseline: 3.2693x; 1.4849x over previous
//
#include <hip/hip_runtime.h>
#include <hip/hip_fp16.h>
#include <stdint.h>

#ifndef JAX_PARTITIONABLE
#define JAX_PARTITIONABLE 1   // JAX >= 0.5 default threefry_partitionable
#endif

typedef _Float16 f16x8 __attribute__((ext_vector_type(8)));
typedef float    f32x4 __attribute__((ext_vector_type(4)));

// ---------------- problem sizes ----------------
static constexpr int BZ   = 8;
static constexpr int QD   = 512;
static constexpr int DIM  = 1024;
static constexpr int I2   = 64;
static constexpr int TOPJ = 128;
static constexpr int NROW = 16384;
static constexpr int NCT  = 8;      // 1024 / 128 col-tiles

// ---------------- ws layout ----------------
// ushort region: AI[kc][16384 rows][64] (hi/lo interleaved chunks), WI[kc][1024][64]
static constexpr size_t EAI = 0;                               // 33,554,432 ushorts
static constexpr size_t EWI = (size_t)33554432;                // 2,097,152 ushorts
// float region starts at float index 17,825,792
static constexpr size_t FQN   = 17825792;            // 8*512
static constexpr size_t FSF   = FQN + 4096;          // 8*4*1024
static constexpr size_t FYS   = FSF + 32768;         // 8*1024
static constexpr size_t FYR   = FYS + 8192;          // 8*1024
static constexpr size_t FY2   = FYR + 8192;          // 8*4*1024
static constexpr size_t FGQ   = FY2 + 32768;         // 8*1024
static constexpr size_t FSG   = FGQ + 8192;          // 8
static constexpr size_t FCL   = FSG + 8;             // 8
static constexpr size_t FMS   = FCL + 8;             // 8*2*4
static constexpr size_t FP2   = FMS + 64;            // 64*256
static constexpr size_t FPART = FP2 + 16384;         // NCT*16384*3 = 393,216
// end = 18,235,552 floats ~= 72.9 MB

// ---------------- threefry2x32 (JAX-exact) ----------------
__device__ __forceinline__ uint32_t rotl32(uint32_t v, int d){ return (v << d) | (v >> (32 - d)); }

__device__ __forceinline__ void tf2x32(uint32_t k0, uint32_t k1, uint32_t x0, uint32_t x1,
                                       uint32_t& o0, uint32_t& o1){
  const uint32_t ks2 = k0 ^ k1 ^ 0x1BD11BDAu;
  x0 += k0; x1 += k1;
#define TFR(r) x0 += x1; x1 = rotl32(x1, r); x1 ^= x0;
  TFR(13) TFR(15) TFR(26) TFR(6)
  x0 += k1;  x1 += ks2 + 1u;
  TFR(17) TFR(29) TFR(16) TFR(24)
  x0 += ks2; x1 += k0 + 2u;
  TFR(13) TFR(15) TFR(26) TFR(6)
  x0 += k0;  x1 += k1 + 3u;
  TFR(17) TFR(29) TFR(16) TFR(24)
  x0 += k1;  x1 += ks2 + 4u;
  TFR(13) TFR(15) TFR(26) TFR(6)
  x0 += ks2; x1 += k0 + 5u;
#undef TFR
  o0 = x0; o1 = x1;
}

__device__ __forceinline__ void jax_keys(uint32_t& k1a, uint32_t& k1b, uint32_t& k2a, uint32_t& k2b){
#if JAX_PARTITIONABLE
  uint32_t a,b,c,d;
  tf2x32(0u, 42u, 0u, 0u, a, b);
  tf2x32(0u, 42u, 0u, 1u, c, d);
  k1a = a; k1b = b; k2a = c; k2b = d;
#else
  uint32_t a,b,c,d;
  tf2x32(0u, 42u, 0u, 2u, a, b);
  tf2x32(0u, 42u, 1u, 3u, c, d);
  k1a = a; k1b = c; k2a = b; k2b = d;
#endif
}

__device__ __forceinline__ float jax_uniform(uint32_t ka, uint32_t kb, uint32_t idx, uint32_t half_n){
  uint32_t o0, o1, bits;
#if JAX_PARTITIONABLE
  (void)half_n;
  tf2x32(ka, kb, 0u, idx, o0, o1);
  bits = o0 ^ o1;
#else
  if (idx < half_n){ tf2x32(ka, kb, idx, idx + half_n, o0, o1); bits = o0; }
  else             { tf2x32(ka, kb, idx - half_n, idx, o0, o1); bits = o1; }
#endif
  float f = __uint_as_float((bits >> 9) | 0x3f800000u) - 1.0f;
  f = f + 1e-20f;
  return fmaxf(f, 1e-20f);
}

// ---------------- block reductions ----------------
__device__ __forceinline__ float blk_sum(float v, float* red){
  const int tid = threadIdx.x;
  red[tid] = v; __syncthreads();
  #pragma unroll
  for (int s = 128; s > 0; s >>= 1){
    if (tid < s) red[tid] += red[tid + s];
    __syncthreads();
  }
  float r = red[0]; __syncthreads();
  return r;
}
__device__ __forceinline__ float blk_max(float v, float* red){
  const int tid = threadIdx.x;
  red[tid] = v; __syncthreads();
  #pragma unroll
  for (int s = 128; s > 0; s >>= 1){
    if (tid < s) red[tid] = fmaxf(red[tid], red[tid + s]);
    __syncthreads();
  }
  float r = red[0]; __syncthreads();
  return r;
}

// ---------------- fp16 split helpers ----------------
__device__ __forceinline__ unsigned short f2h(float x){
  return __half_as_ushort(__float2half(x));
}
__device__ __forceinline__ float h2f(unsigned short u){
  return __half2float(__ushort_as_half(u));
}

// ---------------- async global->LDS (16B/lane) ----------------
__device__ __forceinline__ void gl_lds16(const void* g, void* l){
  __builtin_amdgcn_global_load_lds((const __attribute__((address_space(1))) void*)g,
                                   (__attribute__((address_space(3))) void*)l, 16, 0, 0);
}

// ================= K1: norms (q, video_cls) -> qn, seg_feat =================
__global__ __launch_bounds__(256) void k_norm(const float* __restrict__ qf,
                                              const float* __restrict__ vcls,
                                              float* __restrict__ ws)
{
  const int b = blockIdx.x, tid = threadIdx.x;
  __shared__ float red[256];
  float q0 = qf[b * QD + tid];
  float q1 = qf[b * QD + 256 + tid];
  float ss = blk_sum(q0*q0 + q1*q1, red);
  float nrm = sqrtf(ss);
  ws[FQN + (size_t)b * QD + tid]       = q0 / nrm;
  ws[FQN + (size_t)b * QD + 256 + tid] = q1 / nrm;

  float sf[4][4];
  #pragma unroll
  for (int c = 0; c < 4; ++c)
    #pragma unroll
    for (int r = 0; r < 4; ++r) sf[c][r] = 0.f;

  for (int f = 0; f < 16; ++f){
    float v[4]; float s2 = 0.f;
    #pragma unroll
    for (int r = 0; r < 4; ++r){
      v[r] = vcls[((size_t)(b * 16 + f)) * DIM + tid + (r << 8)];
      s2 += v[r] * v[r];
    }
    float s = blk_sum(s2, red);
    float n2 = sqrtf(s);
    const int c = f >> 2;
    #pragma unroll
    for (int r = 0; r < 4; ++r) sf[c][r] += v[r] / n2;
  }
  #pragma unroll
  for (int c = 0; c < 4; ++c)
    #pragma unroll
    for (int r = 0; r < 4; ++r)
      ws[FSF + ((size_t)(b * 4 + c)) * DIM + tid + (r << 8)] = sf[c][r] * 0.25f;
}

// ================= K2: W -> interleaved hi/lo fp16 (WI[kc][row][64]) =================
__global__ __launch_bounds__(256) void k_wsplit(const float* __restrict__ W,
                                                float* __restrict__ ws)
{
  unsigned short* WI = (unsigned short*)ws + EWI;
  const int row = blockIdx.x;          // 0..1023
  const int t = threadIdx.x;           // elems 4t..4t+3
  const int kc = t >> 3;
  const int c  = (t & 7) >> 1;         // hi 16B chunk 0..3
  const int pos = (t & 1) * 4;
  float4 v = *(const float4*)&W[(size_t)row * DIM + t * 4];
  ushort4 h, l;
  h.x = f2h(v.x); l.x = f2h(v.x - h2f(h.x));
  h.y = f2h(v.y); l.y = f2h(v.y - h2f(h.y));
  h.z = f2h(v.z); l.z = f2h(v.z - h2f(h.z));
  h.w = f2h(v.w); l.w = f2h(v.w - h2f(h.w));
  const size_t base = ((size_t)kc * 1024 + row) * 64;
  *(ushort4*)&WI[base + c * 8 + pos]      = h;
  *(ushort4*)&WI[base + c * 8 + pos + 32] = l;
}

// ================= K3: distributed matvecs =================
__global__ __launch_bounds__(256) void k_matvec(
    const float* __restrict__ sWq, const float* __restrict__ sbq,
    const float* __restrict__ rWq, const float* __restrict__ rbq,
    const float* __restrict__ sWk, const float* __restrict__ sbk,
    float* __restrict__ ws)
{
  const int bid = blockIdx.x;
  const int b = bid >> 5, ch = bid & 31;
  const int tid = threadIdx.x;
  const int di = tid >> 3, sub = tid & 7;
  const int d = ch * 32 + di;
  const float* qn = ws + FQN + (size_t)b * QD;
  const float* sf = ws + FSF + (size_t)b * 4 * DIM;

  {
    const float* wr = sWq + (size_t)d * QD + sub * 64;
    const float* qq = qn + sub * 64;
    float a = 0.f;
    #pragma unroll
    for (int e = 0; e < 64; e += 4){
      float4 w4 = *(const float4*)(wr + e);
      a += qq[e]*w4.x + qq[e+1]*w4.y + qq[e+2]*w4.z + qq[e+3]*w4.w;
    }
    a += __shfl_xor(a, 1); a += __shfl_xor(a, 2); a += __shfl_xor(a, 4);
    if (sub == 0) ws[FYS + (size_t)b * DIM + d] = a + sbq[d];
  }
  {
    const float* wr = rWq + (size_t)d * QD + sub * 64;
    const float* qq = qn + sub * 64;
    float a = 0.f;
    #pragma unroll
    for (int e = 0; e < 64; e += 4){
      float4 w4 = *(const float4*)(wr + e);
      a += qq[e]*w4.x + qq[e+1]*w4.y + qq[e+2]*w4.z + qq[e+3]*w4.w;
    }
    a += __shfl_xor(a, 1); a += __shfl_xor(a, 2); a += __shfl_xor(a, 4);
    if (sub == 0) ws[FYR + (size_t)b * DIM + d] = a + rbq[d];
  }
  for (int c = 0; c < 4; ++c){
    const float* wr = sWk + (size_t)d * DIM + sub * 128;
    const float* qq = sf + (size_t)c * DIM + sub * 128;
    float a = 0.f;
    #pragma unroll
    for (int e = 0; e < 128; e += 4){
      float4 w4 = *(const float4*)(wr + e);
      a += qq[e]*w4.x + qq[e+1]*w4.y + qq[e+2]*w4.z + qq[e+3]*w4.w;
    }
    a += __shfl_xor(a, 1); a += __shfl_xor(a, 2); a += __shfl_xor(a, 4);
    if (sub == 0) ws[FY2 + ((size_t)(b * 4 + c)) * DIM + d] = a + sbk[d];
  }
}

// ================= K4: LN finishers + seg softmax/gumbel masks =================
__global__ __launch_bounds__(256) void k_post(
    const float* __restrict__ slnqg, const float* __restrict__ slnqb,
    const float* __restrict__ rlnqg, const float* __restrict__ rlnqb,
    const float* __restrict__ rlnkg, const float* __restrict__ rlnkb,
    const float* __restrict__ slnkg, const float* __restrict__ slnkb,
    float* __restrict__ ws)
{
  const int b = blockIdx.x, tid = threadIdx.x;
  __shared__ float red[256];
  __shared__ float qps[DIM];
  __shared__ float lg[4];

  {
    float y[4];
    #pragma unroll
    for (int r = 0; r < 4; ++r) y[r] = ws[FYS + (size_t)b * DIM + tid + (r << 8)];
    float S = blk_sum(y[0]+y[1]+y[2]+y[3], red);
    float mu = S * (1.f / 1024.f);
    float pv = 0.f;
    #pragma unroll
    for (int r = 0; r < 4; ++r){ float dv = y[r]-mu; pv += dv*dv; }
    float V = blk_sum(pv, red);
    float sig = sqrtf(V * (1.f / 1024.f) + 1e-12f);
    #pragma unroll
    for (int r = 0; r < 4; ++r){
      const int d = tid + (r << 8);
      qps[d] = (y[r]-mu)/sig * slnqg[d] + slnqb[d];
    }
  }
  __syncthreads();

  {
    float y[4];
    #pragma unroll
    for (int r = 0; r < 4; ++r) y[r] = ws[FYR + (size_t)b * DIM + tid + (r << 8)];
    float S = blk_sum(y[0]+y[1]+y[2]+y[3], red);
    float mu = S * (1.f / 1024.f);
    float pv = 0.f;
    #pragma unroll
    for (int r = 0; r < 4; ++r){ float dv = y[r]-mu; pv += dv*dv; }
    float V = blk_sum(pv, red);
    float sig = sqrtf(V * (1.f / 1024.f) + 1e-12f);
    float sg = 0.f, cl = 0.f;
    #pragma unroll
    for (int r = 0; r < 4; ++r){
      const int d = tid + (r << 8);
      float o = (y[r]-mu)/sig * rlnqg[d] + rlnqb[d];
      float gv = rlnkg[d] * o;
      ws[FGQ + (size_t)b * DIM + d] = gv;
      sg += gv;
      cl += rlnkb[d] * o;
    }
    float SG = blk_sum(sg, red);
    float CL = blk_sum(cl, red);
    if (tid == 0){ ws[FSG + b] = SG; ws[FCL + b] = CL; }
  }

  for (int c = 0; c < 4; ++c){
    float y[4];
    #pragma unroll
    for (int r = 0; r < 4; ++r) y[r] = ws[FY2 + ((size_t)(b * 4 + c)) * DIM + tid + (r << 8)];
    float S = blk_sum(y[0]+y[1]+y[2]+y[3], red);
    float mu = S * (1.f / 1024.f);
    float pv = 0.f;
    #pragma unroll
    for (int r = 0; r < 4; ++r){ float dv = y[r]-mu; pv += dv*dv; }
    float V = blk_sum(pv, red);
    float sig = sqrtf(V * (1.f / 1024.f) + 1e-12f);
    float lp = 0.f;
    #pragma unroll
    for (int r = 0; r < 4; ++r){
      const int d = tid + (r << 8);
      float kp = (y[r]-mu)/sig * slnkg[d] + slnkb[d];
      lp += kp * qps[d];
    }
    float L = blk_sum(lp, red);
    if (tid == 0) lg[c] = L;
  }
  __syncthreads();

  if (tid == 0){
    float m = fmaxf(fmaxf(lg[0], lg[1]), fmaxf(lg[2], lg[3]));
    float e[4], s = 0.f;
    #pragma unroll
    for (int c = 0; c < 4; ++c){ e[c] = expf(lg[c] - m); s += e[c]; }
    float probs[4];
    #pragma unroll
    for (int c = 0; c < 4; ++c) probs[c] = e[c] / s;
    uint32_t k1a, k1b, k2a, k2b;
    jax_keys(k1a, k1b, k2a, k2b);
    for (int t = 0; t < 2; ++t){
      float x[4];
      #pragma unroll
      for (int c = 0; c < 4; ++c){
        float u = jax_uniform(k1a, k1b, (uint32_t)(b * 8 + t * 4 + c), 32u);
        float gmb = -logf(-logf(u));
        x[c] = (probs[c] + gmb) / 1e-6f;
      }
      float xm = fmaxf(fmaxf(x[0], x[1]), fmaxf(x[2], x[3]));
      float w[4], sw = 0.f;
      #pragma unroll
      for (int c = 0; c < 4; ++c){ w[c] = expf(x[c] - xm); sw += w[c]; }
      #pragma unroll
      for (int c = 0; c < 4; ++c) ws[FMS + b * 8 + t * 4 + c] = w[c] / sw;
    }
  }
}

// ================= K5: sel rows -> interleaved hi/lo fp16 (AI[kc][row][64]) =================
__global__ __launch_bounds__(256) void k_sel(const float* __restrict__ E,
                                             float* __restrict__ ws)
{
  const int bid = blockIdx.x;
  const int i = bid >> 8, p = bid & 255;
  const int bz = i >> 3, it = i & 7, t = it >> 2, j = it & 3;
  const int row = i * 256 + p;
  const int th = threadIdx.x;
  const int d = th << 2;
  const float* msk = ws + FMS + bz * 8 + t * 4;
  float4 a = {0.f, 0.f, 0.f, 0.f};
  #pragma unroll
  for (int c = 0; c < 4; ++c){
    const float w = msk[c];
    if (w != 0.f){
      const float4 v = *(const float4*)&E[(((size_t)((bz * 4 + c) * 4 + j)) * 256 + p) * DIM + d];
      a.x += w * v.x; a.y += w * v.y; a.z += w * v.z; a.w += w * v.w;
    }
  }
  unsigned short* AI = (unsigned short*)ws + EAI;
  const int kc = th >> 3;
  const int c  = (th & 7) >> 1;
  const int pos = (th & 1) * 4;
  ushort4 h, l;
  h.x = f2h(a.x); l.x = f2h(a.x - h2f(h.x));
  h.y = f2h(a.y); l.y = f2h(a.y - h2f(h.y));
  h.z = f2h(a.z); l.z = f2h(a.z - h2f(h.z));
  h.w = f2h(a.w); l.w = f2h(a.w - h2f(h.w));
  const size_t base = ((size_t)kc * NROW + row) * 64;
  *(ushort4*)&AI[base + c * 8 + pos]      = h;
  *(ushort4*)&AI[base + c * 8 + pos + 32] = l;
}

// ================= K6: split-fp16 MFMA GEMM, fused LN/logit stats =================
// block tile 256 rows x 128 cols, BK=32, 8 waves (4 row x 2 col), wave tile 64x64.
// LDS: Abuf 2x32KB + Bbuf 2x16KB = 96KB. Coalesced gl_lds16 (1024B contiguous),
// chunk^=(row&7) swizzle applied identically on source-permute and ds_read.
__global__ __launch_bounds__(512, 2) void k_gemm(const float* __restrict__ bk,
                                                 float* __restrict__ ws)
{
  const unsigned short* AI = (const unsigned short*)ws + EAI;
  const unsigned short* WI = (const unsigned short*)ws + EWI;
  const float* gq = ws + FGQ;
  float* part = ws + FPART;

  __shared__ __align__(16) unsigned short Abuf[2][16384];  // 2 x 256 rows x 64
  __shared__ __align__(16) unsigned short Bbuf[2][8192];   // 2 x 128 rows x 64

  const int ct = blockIdx.x;           // 0..7
  const int rt = blockIdx.y;           // 0..63
  const int R0 = rt * 256, C0 = ct * 128;
  const int tid = threadIdx.x;
  const int lane = tid & 63, wid = tid >> 6;
  const int wr = wid >> 1, wc = wid & 1;     // 4 x 2 wave grid
  const int b = R0 >> 11;

  // staging constants: lane covers (row = base + (lane>>3), chunk = lane&7),
  // source chunk = (lane&7) ^ (lane>>3)  [involution with the read swizzle]
  const int src_off = (lane >> 3) * 64 + (((lane & 7) ^ (lane >> 3)) << 3);

  // frag read constants: chunk = kgrp ^ (row&7); row&7 == lane&7 here.
  const int pcH = (((lane >> 4) ^ (lane & 7))) * 16;
  const int pcL = pcH ^ 64;
  const int ra = (wr * 64 + (lane & 15)) * 128;
  const int rb = (wc * 64 + (lane & 15)) * 128;

  f32x4 acc[4][4];
  #pragma unroll
  for (int m = 0; m < 4; ++m)
    #pragma unroll
    for (int n = 0; n < 4; ++n)
      acc[m][n] = (f32x4){0.f, 0.f, 0.f, 0.f};

  auto stage = [&](int buf, int kc){
    const unsigned short* Asrc = AI + ((size_t)kc * NROW + R0 + wid * 32) * 64 + src_off;
    const unsigned short* Bsrc = WI + ((size_t)kc * 1024 + C0 + wid * 16) * 64 + src_off;
    unsigned short* Adst = &Abuf[buf][wid * 2048];
    unsigned short* Bdst = &Bbuf[buf][wid * 1024];
    #pragma unroll
    for (int q = 0; q < 4; ++q)
      gl_lds16(Asrc + q * 512, Adst + q * 512);
    #pragma unroll
    for (int q = 0; q < 2; ++q)
      gl_lds16(Bsrc + q * 512, Bdst + q * 512);
  };

  auto compute = [&](int buf){
    const char* pa = (const char*)&Abuf[buf][0] + ra;
    const char* pb = (const char*)&Bbuf[buf][0] + rb;
    f16x8 ah[4], al[4], bh[4], bl[4];
    #pragma unroll
    for (int f = 0; f < 4; ++f){
      ah[f] = *(const f16x8*)(pa + f * 2048 + pcH);
      al[f] = *(const f16x8*)(pa + f * 2048 + pcL);
      bh[f] = *(const f16x8*)(pb + f * 2048 + pcH);
      bl[f] = *(const f16x8*)(pb + f * 2048 + pcL);
    }
    #pragma unroll
    for (int m = 0; m < 4; ++m)
      #pragma unroll
      for (int n = 0; n < 4; ++n){
        acc[m][n] = __builtin_amdgcn_mfma_f32_16x16x32_f16(ah[m], bh[n], acc[m][n], 0, 0, 0);
        acc[m][n] = __builtin_amdgcn_mfma_f32_16x16x32_f16(ah[m], bl[n], acc[m][n], 0, 0, 0);
        acc[m][n] = __builtin_amdgcn_mfma_f32_16x16x32_f16(al[m], bh[n], acc[m][n], 0, 0, 0);
      }
  };

  stage(0, 0);
  __syncthreads();
  for (int t = 0; t < 32; ++t){
    if (t < 31) stage((t & 1) ^ 1, t + 1);
    compute(t & 1);
    __syncthreads();
  }

  // epilogue: per-row stats (sum over cols of this ct-tile)
  float* fred = (float*)&Abuf[0][0];   // 256*2*3 floats = 6KB, overlays Abuf
  float bkv[4], gv[4];
  #pragma unroll
  for (int n = 0; n < 4; ++n){
    const int col = C0 + wc * 64 + n * 16 + (lane & 15);
    bkv[n] = bk[col];
    gv[n]  = gq[(size_t)b * DIM + col];
  }
  #pragma unroll
  for (int m = 0; m < 4; ++m)
    #pragma unroll
    for (int r = 0; r < 4; ++r){
      float s = 0.f, q = 0.f, tt = 0.f;
      #pragma unroll
      for (int n = 0; n < 4; ++n){
        float y = acc[m][n][r] + bkv[n];
        s += y; q += y * y; tt += y * gv[n];
      }
      #pragma unroll
      for (int msk = 8; msk >= 1; msk >>= 1){
        s += __shfl_xor(s, msk); q += __shfl_xor(q, msk); tt += __shfl_xor(tt, msk);
      }
      if ((lane & 15) == 0){
        const int rl = wr * 64 + m * 16 + (lane >> 4) * 4 + r;
        fred[(rl * 2 + wc) * 3 + 0] = s;
        fred[(rl * 2 + wc) * 3 + 1] = q;
        fred[(rl * 2 + wc) * 3 + 2] = tt;
      }
    }
  __syncthreads();
  if (tid < 256){
    #pragma unroll
    for (int st = 0; st < 3; ++st){
      float v = fred[(tid * 2 + 0) * 3 + st] + fred[(tid * 2 + 1) * 3 + st];
      part[((size_t)ct * NROW + R0 + tid) * 3 + st] = v;
    }
  }
}

// ================= K7: finalize logits, softmax over 256 =================
__global__ __launch_bounds__(256) void k_probs2(float* __restrict__ ws)
{
  const int i = blockIdx.x, tid = threadIdx.x;
  const int r = i * 256 + tid;
  const int b = i >> 3;
  __shared__ float red[256];
  const float* part = ws + FPART;
  float S = 0.f, Q = 0.f, T = 0.f;
  #pragma unroll
  for (int ct = 0; ct < NCT; ++ct){
    const float* pp = part + ((size_t)ct * NROW + r) * 3;
    S += pp[0]; Q += pp[1]; T += pp[2];
  }
  float mu  = S * (1.f / 1024.f);
  float var = Q * (1.f / 1024.f) - mu * mu;
  float sig = sqrtf(var + 1e-12f);
  float L = (T - mu * ws[FSG + b]) / sig + ws[FCL + b];
  float M = blk_max(L, red);
  float w = expf(L - M);
  float sw = blk_sum(w, red);
  ws[FP2 + r] = w / sw;
}

// ================= K8: reg gumbel + weighted gather -> out =================
__global__ __launch_bounds__(256) void k_out(const float* __restrict__ E,
                                             const float* __restrict__ ws,
                                             float* __restrict__ out)
{
  const int bid = blockIdx.x;
  const int i = bid >> 7, t2 = bid & 127;
  const int bz = i >> 3, it = i & 7, tt = it >> 2, j = it & 3;
  const int tid = threadIdx.x;
  __shared__ float red[256];
  __shared__ float wv[256];
  __shared__ float mloc[4];
  __shared__ unsigned long long mk[4];

  if (tid < 4) mloc[tid] = ws[FMS + bz * 8 + tt * 4 + tid];

  uint32_t k1a, k1b, k2a, k2b;
  jax_keys(k1a, k1b, k2a, k2b);
  const uint32_t fidx = ((uint32_t)(i * TOPJ + t2)) * 256u + (uint32_t)tid;
  float u = jax_uniform(k2a, k2b, fidx, 1048576u);
  float gmb = -logf(-logf(u));
  float x = (ws[FP2 + (size_t)i * 256 + tid] + gmb) / 1e-6f;
  float M = blk_max(x, red);
  float w = expf(x - M);
  float sw = blk_sum(w, red);
  float wn = w / sw;
  wv[tid] = wn;
  unsigned long long bal = __ballot(wn != 0.f);
  if ((tid & 63) == 0) mk[tid >> 6] = bal;
  __syncthreads();

  const int d = tid << 2;
  float4 acc = {0.f, 0.f, 0.f, 0.f};
  for (int wq = 0; wq < 4; ++wq){
    unsigned long long mm = mk[wq];
    while (mm){
      const int l = __ffsll(mm) - 1;
      mm &= mm - 1;
      const int p = (wq << 6) + l;
      const float wp = wv[p];
      #pragma unroll
      for (int c = 0; c < 4; ++c){
        const float mc = mloc[c];
        if (mc != 0.f){
          const float4 v = *(const float4*)&E[(((size_t)((bz * 4 + c) * 4 + j)) * 256 + p) * DIM + d];
          const float wm = wp * mc;
          acc.x += wm * v.x; acc.y += wm * v.y; acc.z += wm * v.z; acc.w += wm * v.w;
        }
      }
    }
  }
  *(float4*)&out[((size_t)(i * TOPJ + t2)) * DIM + d] = acc;
}

// ---------------- launch ----------------
extern "C" void kernel_launch(void* const* d_in, const int* in_sizes, int n_in,
                              void* d_out, int out_size, void* d_ws, size_t ws_size,
                              hipStream_t stream)
{
  const float* qf    = (const float*)d_in[0];
  const float* E     = (const float*)d_in[1];
  const float* vcls  = (const float*)d_in[2];
  const float* sWq   = (const float*)d_in[3];
  const float* sbq   = (const float*)d_in[4];
  const float* slnqg = (const float*)d_in[5];
  const float* slnqb = (const float*)d_in[6];
  const float* sWk   = (const float*)d_in[7];
  const float* sbk   = (const float*)d_in[8];
  const float* slnkg = (const float*)d_in[9];
  const float* slnkb = (const float*)d_in[10];
  const float* rWq   = (const float*)d_in[11];
  const float* rbq   = (const float*)d_in[12];
  const float* rlnqg = (const float*)d_in[13];
  const float* rlnqb = (const float*)d_in[14];
  const float* rWk   = (const float*)d_in[15];
  const float* rbk   = (const float*)d_in[16];
  const float* rlnkg = (const float*)d_in[17];
  const float* rlnkb = (const float*)d_in[18];
  float* ws  = (float*)d_ws;
  float* out = (float*)d_out;

  k_norm<<<BZ, 256, 0, stream>>>(qf, vcls, ws);
  k_wsplit<<<1024, 256, 0, stream>>>(rWk, ws);
  k_matvec<<<256, 256, 0, stream>>>(sWq, sbq, rWq, rbq, sWk, sbk, ws);
  k_post<<<BZ, 256, 0, stream>>>(slnqg, slnqb, rlnqg, rlnqb, rlnkg, rlnkb, slnkg, slnkb, ws);
  k_sel<<<I2 * 256, 256, 0, stream>>>(E, ws);
  k_gemm<<<dim3(NCT, 64), 512, 0, stream>>>(rbk, ws);
  k_probs2<<<I2, 256, 0, stream>>>(ws);
  k_out<<<I2 * TOPJ, 256, 0, stream>>>(E, ws, out);
}

// Round 4
// 217.598 us; speedup vs baseline: 3.6573x; 1.1187x over previous
//
#include <hip/hip_runtime.h>
#include <hip/hip_fp16.h>
#include <stdint.h>

#ifndef JAX_PARTITIONABLE
#define JAX_PARTITIONABLE 1   // JAX >= 0.5 default threefry_partitionable
#endif

typedef _Float16 f16x8 __attribute__((ext_vector_type(8)));
typedef float    f32x4 __attribute__((ext_vector_type(4)));

// ---------------- problem sizes ----------------
static constexpr int BZ   = 8;
static constexpr int QD   = 512;
static constexpr int DIM  = 1024;
static constexpr int I2   = 64;
static constexpr int TOPJ = 128;
static constexpr int NROW = 16384;
static constexpr int NCT  = 8;      // 1024 / 128 col-tiles

// ---------------- ws layout ----------------
// ushort region: AI[kc][16384 rows][64] (hi/lo interleaved chunks), WI[kc][1024][64]
static constexpr size_t EAI = 0;                               // 33,554,432 ushorts
static constexpr size_t EWI = (size_t)33554432;                // 2,097,152 ushorts
// float region starts at float index 17,825,792
static constexpr size_t FQN   = 17825792;            // 8*512
static constexpr size_t FSF   = FQN + 4096;          // 8*4*1024
static constexpr size_t FYS   = FSF + 32768;         // 8*1024
static constexpr size_t FYR   = FYS + 8192;          // 8*1024
static constexpr size_t FY2   = FYR + 8192;          // 8*4*1024
static constexpr size_t FGQ   = FY2 + 32768;         // 8*1024
static constexpr size_t FSG   = FGQ + 8192;          // 8
static constexpr size_t FCL   = FSG + 8;             // 8
static constexpr size_t FMS   = FCL + 8;             // 8*2*4
static constexpr size_t FP2   = FMS + 64;            // 64*256
static constexpr size_t FPART = FP2 + 16384;         // NCT*16384*3 = 393,216
// end = 18,235,552 floats ~= 72.9 MB

// ---------------- threefry2x32 (JAX-exact) ----------------
__device__ __forceinline__ uint32_t rotl32(uint32_t v, int d){ return (v << d) | (v >> (32 - d)); }

__device__ __forceinline__ void tf2x32(uint32_t k0, uint32_t k1, uint32_t x0, uint32_t x1,
                                       uint32_t& o0, uint32_t& o1){
  const uint32_t ks2 = k0 ^ k1 ^ 0x1BD11BDAu;
  x0 += k0; x1 += k1;
#define TFR(r) x0 += x1; x1 = rotl32(x1, r); x1 ^= x0;
  TFR(13) TFR(15) TFR(26) TFR(6)
  x0 += k1;  x1 += ks2 + 1u;
  TFR(17) TFR(29) TFR(16) TFR(24)
  x0 += ks2; x1 += k0 + 2u;
  TFR(13) TFR(15) TFR(26) TFR(6)
  x0 += k0;  x1 += k1 + 3u;
  TFR(17) TFR(29) TFR(16) TFR(24)
  x0 += k1;  x1 += ks2 + 4u;
  TFR(13) TFR(15) TFR(26) TFR(6)
  x0 += ks2; x1 += k0 + 5u;
#undef TFR
  o0 = x0; o1 = x1;
}

__device__ __forceinline__ void jax_keys(uint32_t& k1a, uint32_t& k1b, uint32_t& k2a, uint32_t& k2b){
#if JAX_PARTITIONABLE
  uint32_t a,b,c,d;
  tf2x32(0u, 42u, 0u, 0u, a, b);
  tf2x32(0u, 42u, 0u, 1u, c, d);
  k1a = a; k1b = b; k2a = c; k2b = d;
#else
  uint32_t a,b,c,d;
  tf2x32(0u, 42u, 0u, 2u, a, b);
  tf2x32(0u, 42u, 1u, 3u, c, d);
  k1a = a; k1b = c; k2a = b; k2b = d;
#endif
}

__device__ __forceinline__ float jax_uniform(uint32_t ka, uint32_t kb, uint32_t idx, uint32_t half_n){
  uint32_t o0, o1, bits;
#if JAX_PARTITIONABLE
  (void)half_n;
  tf2x32(ka, kb, 0u, idx, o0, o1);
  bits = o0 ^ o1;
#else
  if (idx < half_n){ tf2x32(ka, kb, idx, idx + half_n, o0, o1); bits = o0; }
  else             { tf2x32(ka, kb, idx - half_n, idx, o0, o1); bits = o1; }
#endif
  float f = __uint_as_float((bits >> 9) | 0x3f800000u) - 1.0f;
  f = f + 1e-20f;
  return fmaxf(f, 1e-20f);
}

// ---------------- block reductions ----------------
__device__ __forceinline__ float blk_sum(float v, float* red){
  const int tid = threadIdx.x;
  red[tid] = v; __syncthreads();
  #pragma unroll
  for (int s = 128; s > 0; s >>= 1){
    if (tid < s) red[tid] += red[tid + s];
    __syncthreads();
  }
  float r = red[0]; __syncthreads();
  return r;
}
__device__ __forceinline__ float blk_max(float v, float* red){
  const int tid = threadIdx.x;
  red[tid] = v; __syncthreads();
  #pragma unroll
  for (int s = 128; s > 0; s >>= 1){
    if (tid < s) red[tid] = fmaxf(red[tid], red[tid + s]);
    __syncthreads();
  }
  float r = red[0]; __syncthreads();
  return r;
}

// ---------------- fp16 split helpers ----------------
__device__ __forceinline__ unsigned short f2h(float x){
  return __half_as_ushort(__float2half(x));
}
__device__ __forceinline__ float h2f(unsigned short u){
  return __half2float(__ushort_as_half(u));
}

// ---------------- async global->LDS (16B/lane) ----------------
__device__ __forceinline__ void gl_lds16(const void* g, void* l){
  __builtin_amdgcn_global_load_lds((const __attribute__((address_space(1))) void*)g,
                                   (__attribute__((address_space(3))) void*)l, 16, 0, 0);
}

// ================= K1: norms (q, video_cls) -> qn, seg_feat =================
__global__ __launch_bounds__(256) void k_norm(const float* __restrict__ qf,
                                              const float* __restrict__ vcls,
                                              float* __restrict__ ws)
{
  const int b = blockIdx.x, tid = threadIdx.x;
  __shared__ float red[256];
  float q0 = qf[b * QD + tid];
  float q1 = qf[b * QD + 256 + tid];
  float ss = blk_sum(q0*q0 + q1*q1, red);
  float nrm = sqrtf(ss);
  ws[FQN + (size_t)b * QD + tid]       = q0 / nrm;
  ws[FQN + (size_t)b * QD + 256 + tid] = q1 / nrm;

  float sf[4][4];
  #pragma unroll
  for (int c = 0; c < 4; ++c)
    #pragma unroll
    for (int r = 0; r < 4; ++r) sf[c][r] = 0.f;

  for (int f = 0; f < 16; ++f){
    float v[4]; float s2 = 0.f;
    #pragma unroll
    for (int r = 0; r < 4; ++r){
      v[r] = vcls[((size_t)(b * 16 + f)) * DIM + tid + (r << 8)];
      s2 += v[r] * v[r];
    }
    float s = blk_sum(s2, red);
    float n2 = sqrtf(s);
    const int c = f >> 2;
    #pragma unroll
    for (int r = 0; r < 4; ++r) sf[c][r] += v[r] / n2;
  }
  #pragma unroll
  for (int c = 0; c < 4; ++c)
    #pragma unroll
    for (int r = 0; r < 4; ++r)
      ws[FSF + ((size_t)(b * 4 + c)) * DIM + tid + (r << 8)] = sf[c][r] * 0.25f;
}

// ================= K2: W -> interleaved hi/lo fp16 (WI[kc][row][64]) =================
__global__ __launch_bounds__(256) void k_wsplit(const float* __restrict__ W,
                                                float* __restrict__ ws)
{
  unsigned short* WI = (unsigned short*)ws + EWI;
  const int row = blockIdx.x;          // 0..1023
  const int t = threadIdx.x;           // elems 4t..4t+3
  const int kc = t >> 3;
  const int c  = (t & 7) >> 1;         // hi 16B chunk 0..3
  const int pos = (t & 1) * 4;
  float4 v = *(const float4*)&W[(size_t)row * DIM + t * 4];
  ushort4 h, l;
  h.x = f2h(v.x); l.x = f2h(v.x - h2f(h.x));
  h.y = f2h(v.y); l.y = f2h(v.y - h2f(h.y));
  h.z = f2h(v.z); l.z = f2h(v.z - h2f(h.z));
  h.w = f2h(v.w); l.w = f2h(v.w - h2f(h.w));
  const size_t base = ((size_t)kc * 1024 + row) * 64;
  *(ushort4*)&WI[base + c * 8 + pos]      = h;
  *(ushort4*)&WI[base + c * 8 + pos + 32] = l;
}

// ================= K3: distributed matvecs =================
__global__ __launch_bounds__(256) void k_matvec(
    const float* __restrict__ sWq, const float* __restrict__ sbq,
    const float* __restrict__ rWq, const float* __restrict__ rbq,
    const float* __restrict__ sWk, const float* __restrict__ sbk,
    float* __restrict__ ws)
{
  const int bid = blockIdx.x;
  const int b = bid >> 5, ch = bid & 31;
  const int tid = threadIdx.x;
  const int di = tid >> 3, sub = tid & 7;
  const int d = ch * 32 + di;
  const float* qn = ws + FQN + (size_t)b * QD;
  const float* sf = ws + FSF + (size_t)b * 4 * DIM;

  {
    const float* wr = sWq + (size_t)d * QD + sub * 64;
    const float* qq = qn + sub * 64;
    float a = 0.f;
    #pragma unroll
    for (int e = 0; e < 64; e += 4){
      float4 w4 = *(const float4*)(wr + e);
      a += qq[e]*w4.x + qq[e+1]*w4.y + qq[e+2]*w4.z + qq[e+3]*w4.w;
    }
    a += __shfl_xor(a, 1); a += __shfl_xor(a, 2); a += __shfl_xor(a, 4);
    if (sub == 0) ws[FYS + (size_t)b * DIM + d] = a + sbq[d];
  }
  {
    const float* wr = rWq + (size_t)d * QD + sub * 64;
    const float* qq = qn + sub * 64;
    float a = 0.f;
    #pragma unroll
    for (int e = 0; e < 64; e += 4){
      float4 w4 = *(const float4*)(wr + e);
      a += qq[e]*w4.x + qq[e+1]*w4.y + qq[e+2]*w4.z + qq[e+3]*w4.w;
    }
    a += __shfl_xor(a, 1); a += __shfl_xor(a, 2); a += __shfl_xor(a, 4);
    if (sub == 0) ws[FYR + (size_t)b * DIM + d] = a + rbq[d];
  }
  for (int c = 0; c < 4; ++c){
    const float* wr = sWk + (size_t)d * DIM + sub * 128;
    const float* qq = sf + (size_t)c * DIM + sub * 128;
    float a = 0.f;
    #pragma unroll
    for (int e = 0; e < 128; e += 4){
      float4 w4 = *(const float4*)(wr + e);
      a += qq[e]*w4.x + qq[e+1]*w4.y + qq[e+2]*w4.z + qq[e+3]*w4.w;
    }
    a += __shfl_xor(a, 1); a += __shfl_xor(a, 2); a += __shfl_xor(a, 4);
    if (sub == 0) ws[FY2 + ((size_t)(b * 4 + c)) * DIM + d] = a + sbk[d];
  }
}

// ================= K4: LN finishers + seg softmax/gumbel masks =================
__global__ __launch_bounds__(256) void k_post(
    const float* __restrict__ slnqg, const float* __restrict__ slnqb,
    const float* __restrict__ rlnqg, const float* __restrict__ rlnqb,
    const float* __restrict__ rlnkg, const float* __restrict__ rlnkb,
    const float* __restrict__ slnkg, const float* __restrict__ slnkb,
    float* __restrict__ ws)
{
  const int b = blockIdx.x, tid = threadIdx.x;
  __shared__ float red[256];
  __shared__ float qps[DIM];
  __shared__ float lg[4];

  {
    float y[4];
    #pragma unroll
    for (int r = 0; r < 4; ++r) y[r] = ws[FYS + (size_t)b * DIM + tid + (r << 8)];
    float S = blk_sum(y[0]+y[1]+y[2]+y[3], red);
    float mu = S * (1.f / 1024.f);
    float pv = 0.f;
    #pragma unroll
    for (int r = 0; r < 4; ++r){ float dv = y[r]-mu; pv += dv*dv; }
    float V = blk_sum(pv, red);
    float sig = sqrtf(V * (1.f / 1024.f) + 1e-12f);
    #pragma unroll
    for (int r = 0; r < 4; ++r){
      const int d = tid + (r << 8);
      qps[d] = (y[r]-mu)/sig * slnqg[d] + slnqb[d];
    }
  }
  __syncthreads();

  {
    float y[4];
    #pragma unroll
    for (int r = 0; r < 4; ++r) y[r] = ws[FYR + (size_t)b * DIM + tid + (r << 8)];
    float S = blk_sum(y[0]+y[1]+y[2]+y[3], red);
    float mu = S * (1.f / 1024.f);
    float pv = 0.f;
    #pragma unroll
    for (int r = 0; r < 4; ++r){ float dv = y[r]-mu; pv += dv*dv; }
    float V = blk_sum(pv, red);
    float sig = sqrtf(V * (1.f / 1024.f) + 1e-12f);
    float sg = 0.f, cl = 0.f;
    #pragma unroll
    for (int r = 0; r < 4; ++r){
      const int d = tid + (r << 8);
      float o = (y[r]-mu)/sig * rlnqg[d] + rlnqb[d];
      float gv = rlnkg[d] * o;
      ws[FGQ + (size_t)b * DIM + d] = gv;
      sg += gv;
      cl += rlnkb[d] * o;
    }
    float SG = blk_sum(sg, red);
    float CL = blk_sum(cl, red);
    if (tid == 0){ ws[FSG + b] = SG; ws[FCL + b] = CL; }
  }

  for (int c = 0; c < 4; ++c){
    float y[4];
    #pragma unroll
    for (int r = 0; r < 4; ++r) y[r] = ws[FY2 + ((size_t)(b * 4 + c)) * DIM + tid + (r << 8)];
    float S = blk_sum(y[0]+y[1]+y[2]+y[3], red);
    float mu = S * (1.f / 1024.f);
    float pv = 0.f;
    #pragma unroll
    for (int r = 0; r < 4; ++r){ float dv = y[r]-mu; pv += dv*dv; }
    float V = blk_sum(pv, red);
    float sig = sqrtf(V * (1.f / 1024.f) + 1e-12f);
    float lp = 0.f;
    #pragma unroll
    for (int r = 0; r < 4; ++r){
      const int d = tid + (r << 8);
      float kp = (y[r]-mu)/sig * slnkg[d] + slnkb[d];
      lp += kp * qps[d];
    }
    float L = blk_sum(lp, red);
    if (tid == 0) lg[c] = L;
  }
  __syncthreads();

  if (tid == 0){
    float m = fmaxf(fmaxf(lg[0], lg[1]), fmaxf(lg[2], lg[3]));
    float e[4], s = 0.f;
    #pragma unroll
    for (int c = 0; c < 4; ++c){ e[c] = expf(lg[c] - m); s += e[c]; }
    float probs[4];
    #pragma unroll
    for (int c = 0; c < 4; ++c) probs[c] = e[c] / s;
    uint32_t k1a, k1b, k2a, k2b;
    jax_keys(k1a, k1b, k2a, k2b);
    for (int t = 0; t < 2; ++t){
      float x[4];
      #pragma unroll
      for (int c = 0; c < 4; ++c){
        float u = jax_uniform(k1a, k1b, (uint32_t)(b * 8 + t * 4 + c), 32u);
        float gmb = -logf(-logf(u));
        x[c] = (probs[c] + gmb) / 1e-6f;
      }
      float xm = fmaxf(fmaxf(x[0], x[1]), fmaxf(x[2], x[3]));
      float w[4], sw = 0.f;
      #pragma unroll
      for (int c = 0; c < 4; ++c){ w[c] = expf(x[c] - xm); sw += w[c]; }
      #pragma unroll
      for (int c = 0; c < 4; ++c) ws[FMS + b * 8 + t * 4 + c] = w[c] / sw;
    }
  }
}

// ================= K5: sel rows -> interleaved hi/lo fp16 (AI[kc][row][64]) =================
__global__ __launch_bounds__(256) void k_sel(const float* __restrict__ E,
                                             float* __restrict__ ws)
{
  const int bid = blockIdx.x;
  const int i = bid >> 8, p = bid & 255;
  const int bz = i >> 3, it = i & 7, t = it >> 2, j = it & 3;
  const int row = i * 256 + p;
  const int th = threadIdx.x;
  const int d = th << 2;
  const float* msk = ws + FMS + bz * 8 + t * 4;
  float4 a = {0.f, 0.f, 0.f, 0.f};
  #pragma unroll
  for (int c = 0; c < 4; ++c){
    const float w = msk[c];
    if (w != 0.f){
      const float4 v = *(const float4*)&E[(((size_t)((bz * 4 + c) * 4 + j)) * 256 + p) * DIM + d];
      a.x += w * v.x; a.y += w * v.y; a.z += w * v.z; a.w += w * v.w;
    }
  }
  unsigned short* AI = (unsigned short*)ws + EAI;
  const int kc = th >> 3;
  const int c  = (th & 7) >> 1;
  const int pos = (th & 1) * 4;
  ushort4 h, l;
  h.x = f2h(a.x); l.x = f2h(a.x - h2f(h.x));
  h.y = f2h(a.y); l.y = f2h(a.y - h2f(h.y));
  h.z = f2h(a.z); l.z = f2h(a.z - h2f(h.z));
  h.w = f2h(a.w); l.w = f2h(a.w - h2f(h.w));
  const size_t base = ((size_t)kc * NROW + row) * 64;
  *(ushort4*)&AI[base + c * 8 + pos]      = h;
  *(ushort4*)&AI[base + c * 8 + pos + 32] = l;
}

// ================= K6: split-fp16 MFMA GEMM, fused LN/logit stats =================
// block tile 256 rows x 128 cols, BK=32, 8 waves (4 row x 2 col), wave tile 64x64.
// Double-buffered with COUNTED vmcnt (T4): the 6 next-buffer global_load_lds stay
// in flight across the barrier; raw s_barrier (no vmcnt(0) drain).
// XCD swizzle (T1): xcd k gets rt in [8k,8k+8) with all 8 ct consecutive.
__global__ __launch_bounds__(512) void k_gemm(const float* __restrict__ bk,
                                              float* __restrict__ ws)
{
  const unsigned short* AI = (const unsigned short*)ws + EAI;
  const unsigned short* WI = (const unsigned short*)ws + EWI;
  const float* gq = ws + FGQ;
  float* part = ws + FPART;

  __shared__ __align__(16) unsigned short Abuf[2][16384];  // 2 x 256 rows x 64
  __shared__ __align__(16) unsigned short Bbuf[2][8192];   // 2 x 128 rows x 64

  const int bid = blockIdx.x;                 // 0..511
  const int xcd = bid & 7, idx = bid >> 3;
  const int ct = idx & 7;                     // 0..7
  const int rt = xcd * 8 + (idx >> 3);        // 0..63, contiguous per XCD
  const int R0 = rt * 256, C0 = ct * 128;
  const int tid = threadIdx.x;
  const int lane = tid & 63, wid = tid >> 6;
  const int wr = wid >> 1, wc = wid & 1;      // 4 x 2 wave grid
  const int b = R0 >> 11;

  // epilogue constants loaded FIRST so they retire before vmcnt counting starts
  float bkv[4], gv[4];
  #pragma unroll
  for (int n = 0; n < 4; ++n){
    const int col = C0 + wc * 64 + n * 16 + (lane & 15);
    bkv[n] = bk[col];
    gv[n]  = gq[(size_t)b * DIM + col];
  }

  // staging: lane covers (row = base + (lane>>3), chunk = (lane&7) ^ (lane>>3))
  const int src_off = (lane >> 3) * 64 + (((lane & 7) ^ (lane >> 3)) << 3);
  // frag read: chunk = kgrp ^ (row&7); row&7 == lane&7 here.
  const int pcH = (((lane >> 4) ^ (lane & 7))) * 16;
  const int pcL = pcH ^ 64;
  const int ra = (wr * 64 + (lane & 15)) * 128;
  const int rb = (wc * 64 + (lane & 15)) * 128;

  f32x4 acc[4][4];
  #pragma unroll
  for (int m = 0; m < 4; ++m)
    #pragma unroll
    for (int n = 0; n < 4; ++n)
      acc[m][n] = (f32x4){0.f, 0.f, 0.f, 0.f};

  auto stage = [&](int buf, int kc){
    const unsigned short* Asrc = AI + ((size_t)kc * NROW + R0 + wid * 32) * 64 + src_off;
    const unsigned short* Bsrc = WI + ((size_t)kc * 1024 + C0 + wid * 16) * 64 + src_off;
    unsigned short* Adst = &Abuf[buf][wid * 2048];
    unsigned short* Bdst = &Bbuf[buf][wid * 1024];
    #pragma unroll
    for (int q = 0; q < 4; ++q)
      gl_lds16(Asrc + q * 512, Adst + q * 512);
    #pragma unroll
    for (int q = 0; q < 2; ++q)
      gl_lds16(Bsrc + q * 512, Bdst + q * 512);
  };

  auto compute = [&](int buf){
    const char* pa = (const char*)&Abuf[buf][0] + ra;
    const char* pb = (const char*)&Bbuf[buf][0] + rb;
    f16x8 ah[4], al[4], bh[4], bl[4];
    #pragma unroll
    for (int f = 0; f < 4; ++f){
      ah[f] = *(const f16x8*)(pa + f * 2048 + pcH);
      al[f] = *(const f16x8*)(pa + f * 2048 + pcL);
      bh[f] = *(const f16x8*)(pb + f * 2048 + pcH);
      bl[f] = *(const f16x8*)(pb + f * 2048 + pcL);
    }
    #pragma unroll
    for (int m = 0; m < 4; ++m)
      #pragma unroll
      for (int n = 0; n < 4; ++n){
        acc[m][n] = __builtin_amdgcn_mfma_f32_16x16x32_f16(ah[m], bh[n], acc[m][n], 0, 0, 0);
        acc[m][n] = __builtin_amdgcn_mfma_f32_16x16x32_f16(ah[m], bl[n], acc[m][n], 0, 0, 0);
        acc[m][n] = __builtin_amdgcn_mfma_f32_16x16x32_f16(al[m], bh[n], acc[m][n], 0, 0, 0);
      }
  };

  stage(0, 0);
  #pragma unroll 1
  for (int t = 0; t < 32; ++t){
    if (t < 31){
      stage((t + 1) & 1, t + 1);                       // 6 more loads in flight
      asm volatile("s_waitcnt vmcnt(6)" ::: "memory"); // cur buf landed; next stays flying
    } else {
      asm volatile("s_waitcnt vmcnt(0)" ::: "memory");
    }
    __builtin_amdgcn_s_barrier();                      // all waves' cur-buf loads done
    compute(t & 1);
    asm volatile("s_waitcnt lgkmcnt(0)" ::: "memory"); // all ds_reads of cur buf done
    __builtin_amdgcn_sched_barrier(0);                 // pin: nothing crosses (rule #18)
    __builtin_amdgcn_s_barrier();                      // cur buf reusable next iter
  }

  // epilogue: per-row stats (sum over cols of this ct-tile)
  float* fred = (float*)&Abuf[0][0];   // 256*2*3 floats = 6KB, overlays Abuf
  #pragma unroll
  for (int m = 0; m < 4; ++m)
    #pragma unroll
    for (int r = 0; r < 4; ++r){
      float s = 0.f, q = 0.f, tt = 0.f;
      #pragma unroll
      for (int n = 0; n < 4; ++n){
        float y = acc[m][n][r] + bkv[n];
        s += y; q += y * y; tt += y * gv[n];
      }
      #pragma unroll
      for (int msk = 8; msk >= 1; msk >>= 1){
        s += __shfl_xor(s, msk); q += __shfl_xor(q, msk); tt += __shfl_xor(tt, msk);
      }
      if ((lane & 15) == 0){
        const int rl = wr * 64 + m * 16 + (lane >> 4) * 4 + r;
        fred[(rl * 2 + wc) * 3 + 0] = s;
        fred[(rl * 2 + wc) * 3 + 1] = q;
        fred[(rl * 2 + wc) * 3 + 2] = tt;
      }
    }
  __syncthreads();
  if (tid < 256){
    #pragma unroll
    for (int st = 0; st < 3; ++st){
      float v = fred[(tid * 2 + 0) * 3 + st] + fred[(tid * 2 + 1) * 3 + st];
      part[((size_t)ct * NROW + R0 + tid) * 3 + st] = v;
    }
  }
}

// ================= K7: finalize logits, softmax over 256 =================
__global__ __launch_bounds__(256) void k_probs2(float* __restrict__ ws)
{
  const int i = blockIdx.x, tid = threadIdx.x;
  const int r = i * 256 + tid;
  const int b = i >> 3;
  __shared__ float red[256];
  const float* part = ws + FPART;
  float S = 0.f, Q = 0.f, T = 0.f;
  #pragma unroll
  for (int ct = 0; ct < NCT; ++ct){
    const float* pp = part + ((size_t)ct * NROW + r) * 3;
    S += pp[0]; Q += pp[1]; T += pp[2];
  }
  float mu  = S * (1.f / 1024.f);
  float var = Q * (1.f / 1024.f) - mu * mu;
  float sig = sqrtf(var + 1e-12f);
  float L = (T - mu * ws[FSG + b]) / sig + ws[FCL + b];
  float M = blk_max(L, red);
  float w = expf(L - M);
  float sw = blk_sum(w, red);
  ws[FP2 + r] = w / sw;
}

// ================= K8: reg gumbel + weighted gather -> out =================
__global__ __launch_bounds__(256) void k_out(const float* __restrict__ E,
                                             const float* __restrict__ ws,
                                             float* __restrict__ out)
{
  const int bid = blockIdx.x;
  const int i = bid >> 7, t2 = bid & 127;
  const int bz = i >> 3, it = i & 7, tt = it >> 2, j = it & 3;
  const int tid = threadIdx.x;
  __shared__ float red[256];
  __shared__ float wv[256];
  __shared__ float mloc[4];
  __shared__ unsigned long long mk[4];

  if (tid < 4) mloc[tid] = ws[FMS + bz * 8 + tt * 4 + tid];

  uint32_t k1a, k1b, k2a, k2b;
  jax_keys(k1a, k1b, k2a, k2b);
  const uint32_t fidx = ((uint32_t)(i * TOPJ + t2)) * 256u + (uint32_t)tid;
  float u = jax_uniform(k2a, k2b, fidx, 1048576u);
  float gmb = -logf(-logf(u));
  float x = (ws[FP2 + (size_t)i * 256 + tid] + gmb) / 1e-6f;
  float M = blk_max(x, red);
  float w = expf(x - M);
  float sw = blk_sum(w, red);
  float wn = w / sw;
  wv[tid] = wn;
  unsigned long long bal = __ballot(wn != 0.f);
  if ((tid & 63) == 0) mk[tid >> 6] = bal;
  __syncthreads();

  const int d = tid << 2;
  float4 acc = {0.f, 0.f, 0.f, 0.f};
  for (int wq = 0; wq < 4; ++wq){
    unsigned long long mm = mk[wq];
    while (mm){
      const int l = __ffsll(mm) - 1;
      mm &= mm - 1;
      const int p = (wq << 6) + l;
      const float wp = wv[p];
      #pragma unroll
      for (int c = 0; c < 4; ++c){
        const float mc = mloc[c];
        if (mc != 0.f){
          const float4 v = *(const float4*)&E[(((size_t)((bz * 4 + c) * 4 + j)) * 256 + p) * DIM + d];
          const float wm = wp * mc;
          acc.x += wm * v.x; acc.y += wm * v.y; acc.z += wm * v.z; acc.w += wm * v.w;
        }
      }
    }
  }
  *(float4*)&out[((size_t)(i * TOPJ + t2)) * DIM + d] = acc;
}

// ---------------- launch ----------------
extern "C" void kernel_launch(void* const* d_in, const int* in_sizes, int n_in,
                              void* d_out, int out_size, void* d_ws, size_t ws_size,
                              hipStream_t stream)
{
  const float* qf    = (const float*)d_in[0];
  const float* E     = (const float*)d_in[1];
  const float* vcls  = (const float*)d_in[2];
  const float* sWq   = (const float*)d_in[3];
  const float* sbq   = (const float*)d_in[4];
  const float* slnqg = (const float*)d_in[5];
  const float* slnqb = (const float*)d_in[6];
  const float* sWk   = (const float*)d_in[7];
  const float* sbk   = (const float*)d_in[8];
  const float* slnkg = (const float*)d_in[9];
  const float* slnkb = (const float*)d_in[10];
  const float* rWq   = (const float*)d_in[11];
  const float* rbq   = (const float*)d_in[12];
  const float* rlnqg = (const float*)d_in[13];
  const float* rlnqb = (const float*)d_in[14];
  const float* rWk   = (const float*)d_in[15];
  const float* rbk   = (const float*)d_in[16];
  const float* rlnkg = (const float*)d_in[17];
  const float* rlnkb = (const float*)d_in[18];
  float* ws  = (float*)d_ws;
  float* out = (float*)d_out;

  k_norm<<<BZ, 256, 0, stream>>>(qf, vcls, ws);
  k_wsplit<<<1024, 256, 0, stream>>>(rWk, ws);
  k_matvec<<<256, 256, 0, stream>>>(sWq, sbq, rWq, rbq, sWk, sbk, ws);
  k_post<<<BZ, 256, 0, stream>>>(slnqg, slnqb, rlnqg, rlnqb, rlnkg, rlnkb, slnkg, slnkb, ws);
  k_sel<<<I2 * 256, 256, 0, stream>>>(E, ws);
  k_gemm<<<512, 512, 0, stream>>>(rbk, ws);
  k_probs2<<<I2, 256, 0, stream>>>(ws);
  k_out<<<I2 * TOPJ, 256, 0, stream>>>(E, ws, out);
}